// Round 4
// baseline (2374.660 us; speedup 1.0000x reference)
//
#include <hip/hip_runtime.h>
#include <cstddef>

#define DEVFN __device__ __forceinline__

constexpr int N0   = 2712;             // 768+640+704+600
constexpr int MAXL = 768;
constexpr int NBAT = 4;
constexpr int E    = 512;
constexpr int F    = 1024;
constexpr int HID  = 160;
constexpr int WSZ  = 16;               // window length
constexpr int NY   = 2 * WSZ * HID;    // 5120: [u | d] fused Y width
constexpr size_t NOFF = (size_t)-1;

// ---------------- static device scratch pool (offsets in floats) ----------------
constexpr size_t oXF    = 0;
constexpr size_t oKV0   = oXF    + (size_t)N0*E;
constexpr size_t oQH    = oKV0   + (size_t)N0*F;
constexpr size_t oHU0   = oQH    + (size_t)N0*E;
constexpr size_t oEU0   = oHU0   + (size_t)N0*HID;
constexpr size_t oHD0   = oEU0   + (size_t)N0;
constexpr size_t oDAT1  = oHD0   + (size_t)N0*HID;
constexpr size_t oHU1   = oDAT1  + (size_t)N0*F;
constexpr size_t oEU1   = oHU1   + (size_t)N0*HID;
constexpr size_t oHD1   = oEU1   + (size_t)N0;
constexpr size_t oDAT2  = oHD1   + (size_t)N0*HID;
constexpr size_t oKH0   = oDAT2  + (size_t)N0*F;
constexpr size_t oVH0   = oKH0   + (size_t)N0*E;
constexpr size_t oBH0K  = oVH0   + (size_t)N0*E;
constexpr size_t oBH0V  = oBH0K  + (size_t)15*E;
constexpr size_t oDH1K  = oBH0V  + (size_t)15*E;
constexpr size_t oDH1V  = oDH1K  + (size_t)N0*E;
constexpr size_t oDH2K  = oDH1V  + (size_t)N0*E;
constexpr size_t oDH2V  = oDH2K  + (size_t)N0*E;
constexpr size_t oCTX   = oDH2V  + (size_t)N0*E;
constexpr size_t oY2    = oCTX   + (size_t)N0*E;
constexpr size_t oEUS0  = oY2    + (size_t)N0*E;
constexpr size_t oEUS1  = oEUS0  + (size_t)N0;
constexpr size_t oSEL0  = oEUS1  + (size_t)N0;
constexpr size_t oTM0   = oSEL0  + (size_t)N0;
constexpr size_t oSEL1  = oTM0   + (size_t)N0;
constexpr size_t oTM1   = oSEL1  + (size_t)N0;
constexpr size_t oB0    = oTM1   + (size_t)N0;
constexpr size_t oB1    = oB0    + 8;
constexpr size_t oB2    = oB1    + 8;
constexpr size_t oWQC   = oB2    + 8;
constexpr size_t oBQC   = oWQC   + (size_t)E*E;
constexpr size_t oWOP   = oBQC   + E;
constexpr size_t oBOP   = oWOP   + (size_t)E*E;
constexpr size_t oBD0   = oBOP   + E;
constexpr size_t oBD1   = oBD0   + (size_t)F*NY;
constexpr size_t oBUFY0 = oBD1   + (size_t)F*NY;
constexpr size_t oBUFY1 = oBUFY0 + (size_t)15*NY;
constexpr size_t oYB    = oBUFY1 + (size_t)15*NY;
constexpr size_t oEND   = oYB    + (size_t)N0*NY;

__device__ float g_pool[oEND];   // ~196 MB, allocated at module load (graph-capture safe)

DEVFN float geluf(float x) {
    return 0.5f * x * (1.0f + erff(x / 1.41421356237309504880f));
}

// ---------------- tiny init: level-0 segment bounds ----------------
__global__ void k_init() {
    if (threadIdx.x == 0) {
        int* b = (int*)(g_pool + oB0);
        b[0] = 0; b[1] = 768; b[2] = 1408; b[3] = 2112; b[4] = N0;
    }
}

// ---------------- x (B,768,E) -> x_flat (N0,E) ----------------
__global__ __launch_bounds__(256) void k_xflat(const float* __restrict__ x) {
    int idx = blockIdx.x * 256 + threadIdx.x;
    if (idx >= N0 * E) return;
    int d = idx & (E - 1);
    int g = idx >> 9;
    int s = (g >= 768) + (g >= 1408) + (g >= 2112);
    const int st[4] = {0, 768, 1408, 2112};
    int qp = g - st[s];
    g_pool[oXF + idx] = x[((size_t)s * MAXL + qp) * E + d];
}

// ---------------- w1 (16384,160) pairs -> BD (1024, 5120) ----------------
__global__ __launch_bounds__(256) void k_reshape(
    const float* __restrict__ uw, const float* __restrict__ dw, size_t bdOff)
{
    int idx = blockIdx.x * 256 + threadIdx.x;
    if (idx >= F * NY) return;
    int col = idx % NY;
    int f = idx / NY;
    const float* src = (col < NY / 2) ? uw : dw;
    int rem = (col < NY / 2) ? col : col - NY / 2;
    int j = rem / HID, n = rem % HID;
    g_pool[bdOff + idx] = src[((size_t)j * F + f) * HID + n];
}

// ---------------- out[n] = vec @ W + add ----------------
__global__ __launch_bounds__(256) void k_vecmat(
    const float* __restrict__ vec, const float* __restrict__ W,
    const float* __restrict__ add, size_t outOff, int K, int N)
{
    int n = blockIdx.x * 256 + threadIdx.x;
    if (n >= N) return;
    float s = add[n];
    for (int k = 0; k < K; ++k) s = fmaf(vec[k], W[(size_t)k * N + n], s);
    g_pool[outOff + n] = s;
}

// ---------------- plain f32 GEMM (64x64, 4x4): C = A@B + bias ----------------
__global__ __launch_bounds__(256) void k_pgemm(
    const float* __restrict__ Aext, size_t Aoff, int lda,
    const float* __restrict__ Bext, size_t Boff,
    const float* __restrict__ biasExt, size_t biasOff,
    size_t Coff, int M, size_t mdevOff, int K, int N)
{
    int mval = (mdevOff == NOFF) ? M : *(const int*)(g_pool + mdevOff);
    int row0 = blockIdx.x * 64, col0 = blockIdx.y * 64;
    if (row0 >= mval) return;

    const float* A = Aext ? Aext : (g_pool + Aoff);
    const float* B = Bext ? Bext : (g_pool + Boff);
    const float* bias = biasExt ? biasExt : ((biasOff == NOFF) ? nullptr : g_pool + biasOff);
    float* C = g_pool + Coff;

    __shared__ __align__(16) float As[32][68];
    __shared__ __align__(16) float Bs[32][64];

    int tid = threadIdx.x;
    float acc[4][4] = {};
    int tx = tid & 15, ty = tid >> 4;

    for (int k0 = 0; k0 < K; k0 += 32) {
        #pragma unroll
        for (int l = 0; l < 8; ++l) {
            int idx = tid + l * 256;
            int kk = idx & 31, m = idx >> 5;
            int r = row0 + m;
            float v = 0.0f;
            if (r < mval) v = A[(size_t)r * lda + k0 + kk];
            As[kk][m] = v;
        }
        #pragma unroll
        for (int l = 0; l < 8; ++l) {
            int idx = tid + l * 256;
            int n = idx & 63, kk = idx >> 6;
            int col = col0 + n;
            float v = 0.0f;
            if (col < N) v = B[(size_t)(k0 + kk) * N + col];
            Bs[kk][n] = v;
        }
        __syncthreads();
        #pragma unroll
        for (int kk = 0; kk < 32; ++kk) {
            float4 a4 = *(const float4*)&As[kk][ty * 4];
            float4 b4 = *(const float4*)&Bs[kk][tx * 4];
            float av[4] = {a4.x, a4.y, a4.z, a4.w};
            float bv[4] = {b4.x, b4.y, b4.z, b4.w};
            #pragma unroll
            for (int i = 0; i < 4; ++i)
                #pragma unroll
                for (int jn = 0; jn < 4; ++jn)
                    acc[i][jn] = fmaf(av[i], bv[jn], acc[i][jn]);
        }
        __syncthreads();
    }

    #pragma unroll
    for (int i = 0; i < 4; ++i) {
        int r = row0 + ty * 4 + i;
        if (r >= mval) continue;
        #pragma unroll
        for (int jn = 0; jn < 4; ++jn) {
            int col = col0 + tx * 4 + jn;
            if (col < N)
                C[(size_t)r * N + col] = acc[i][jn] + (bias ? bias[col] : 0.0f);
        }
    }
}

// ---------------- big f32 GEMM (128x128, 8x8): C = A@B  (N must be %128) ----------------
__global__ __launch_bounds__(256) void k_tgemm(
    size_t Aoff, int lda, size_t Boff,
    size_t Coff, int M, size_t mdevOff, int K, int N)
{
    int mval = (mdevOff == NOFF) ? M : *(const int*)(g_pool + mdevOff);
    int row0 = blockIdx.x * 128, col0 = blockIdx.y * 128;
    if (row0 >= mval) return;

    const float* A = g_pool + Aoff;
    const float* B = g_pool + Boff;
    float* C = g_pool + Coff;

    __shared__ __align__(16) float As[16][132];   // transposed: As[k][m]
    __shared__ __align__(16) float Bs[16][128];

    int tid = threadIdx.x;
    int tx = tid & 15, ty = tid >> 4;
    float acc[8][8] = {};

    for (int k0 = 0; k0 < K; k0 += 16) {
        #pragma unroll
        for (int l = 0; l < 2; ++l) {
            int idx = tid + l * 256;
            int r = idx >> 2, kq = (idx & 3) * 4;
            float4 v = make_float4(0.f, 0.f, 0.f, 0.f);
            int rr = row0 + r;
            if (rr < mval) v = *(const float4*)&A[(size_t)rr * lda + k0 + kq];
            As[kq][r] = v.x; As[kq + 1][r] = v.y; As[kq + 2][r] = v.z; As[kq + 3][r] = v.w;
        }
        #pragma unroll
        for (int l = 0; l < 2; ++l) {
            int idx = tid + l * 256;
            int k = idx >> 5, nq = (idx & 31) * 4;
            *(float4*)&Bs[k][nq] = *(const float4*)&B[(size_t)(k0 + k) * N + col0 + nq];
        }
        __syncthreads();
        #pragma unroll
        for (int kk = 0; kk < 16; ++kk) {
            float a0[8], b0[8];
            *(float4*)&a0[0] = *(const float4*)&As[kk][ty * 8];
            *(float4*)&a0[4] = *(const float4*)&As[kk][ty * 8 + 4];
            *(float4*)&b0[0] = *(const float4*)&Bs[kk][tx * 8];
            *(float4*)&b0[4] = *(const float4*)&Bs[kk][tx * 8 + 4];
            #pragma unroll
            for (int i = 0; i < 8; ++i)
                #pragma unroll
                for (int jn = 0; jn < 8; ++jn)
                    acc[i][jn] = fmaf(a0[i], b0[jn], acc[i][jn]);
        }
        __syncthreads();
    }

    #pragma unroll
    for (int i = 0; i < 8; ++i) {
        int r = row0 + ty * 8 + i;
        if (r >= mval) continue;
        float* cp = &C[(size_t)r * N + col0 + tx * 8];
        *(float4*)&cp[0] = *(float4*)&acc[i][0];
        *(float4*)&cp[4] = *(float4*)&acc[i][4];
    }
}

// ---------------- shift-sum epilogue: hu/hd[i][n] = bias[n] + sum_j Ysel(g,j)[cb + j*160 + n] ----------------
__global__ __launch_bounds__(160) void k_shiftsum(
    int colBase, size_t rowmapOff, size_t boundsOff, size_t bufYOff,
    const float* __restrict__ bias, size_t outOff, size_t mdevOff, int M)
{
    int i = blockIdx.x;
    int mval = (mdevOff == NOFF) ? M : *(const int*)(g_pool + mdevOff);
    if (i >= mval) return;
    int n = threadIdx.x;

    const int* bounds = (const int*)(g_pool + boundsOff);
    int g = (rowmapOff == NOFF) ? i : ((const int*)(g_pool + rowmapOff))[i];
    int b1 = bounds[1], b2 = bounds[2], b3 = bounds[3];
    int s = (g >= b1) + (g >= b2) + (g >= b3);
    int st = (s == 0) ? 0 : ((s == 1) ? b1 : ((s == 2) ? b2 : b3));
    int qp = g - st;

    const float* Y = g_pool + oYB;
    const float* bufY = g_pool + bufYOff;

    float acc = bias[n];
    #pragma unroll
    for (int j = 0; j < WSZ; ++j) {
        int sp = qp - j;
        const float* row = (sp >= 0) ? &Y[(size_t)(g - j) * NY]
                                     : &bufY[(size_t)(15 + sp) * NY];
        acc += row[colBase + j * HID + n];
    }
    g_pool[outOff + (size_t)i * HID + n] = acc;
}

// ---------------- eu = elu(gelu(h)@w2 + b2) + 1 ----------------
__global__ __launch_bounds__(64) void k_eu(
    size_t hOff, const float* __restrict__ w2, const float* __restrict__ b2,
    size_t euOff, size_t mdevOff, int M)
{
    int row = blockIdx.x;
    int mval = (mdevOff == NOFF) ? M : *(const int*)(g_pool + mdevOff);
    if (row >= mval) return;
    const float* h = g_pool + hOff;
    int lane = threadIdx.x;
    float s = 0.0f;
    for (int k = lane; k < HID; k += 64)
        s += geluf(h[(size_t)row * HID + k]) * w2[k];
    #pragma unroll
    for (int o = 32; o; o >>= 1) s += __shfl_xor(s, o, 64);
    if (lane == 0) {
        float v = s + b2[0];
        v = (v > 0.0f) ? v : expm1f(v);
        g_pool[euOff + row] = v + 1.0f;
    }
}

// ---------------- selection scan: serial f32 prefix (bit-exact) + parallel rest ----------------
__global__ __launch_bounds__(256) void k_select(
    size_t euOff, size_t boundsOff, int win,
    size_t selOff, size_t tmOff, size_t euSelOff, size_t boundsNextOff)
{
    __shared__ __align__(16) float se[N0];
    __shared__ __align__(16) float run[N0];
    __shared__ int sFlag[N0];
    __shared__ int sSum[256];
    __shared__ float sCz[NBAT];
    __shared__ int sEc[NBAT];
    __shared__ int sB[5];

    int tid = threadIdx.x;
    const int* bounds = (const int*)(g_pool + boundsOff);
    if (tid < 5) sB[tid] = bounds[tid];
    __syncthreads();
    int N = sB[4];
    for (int i = tid; i < N; i += 256) se[i] = g_pool[euOff + i];
    __syncthreads();

    // ---- Phase B: serial f32 inclusive prefix (must match numpy's summation order) ----
    if (tid == 0) {
        float r = 0.0f;
        int g = 0;
        for (; g + 8 <= N; g += 8) {
            float4 a = *(const float4*)&se[g];
            float4 b4 = *(const float4*)&se[g + 4];
            r += a.x;  run[g]     = r;
            r += a.y;  run[g + 1] = r;
            r += a.z;  run[g + 2] = r;
            r += a.w;  run[g + 3] = r;
            r += b4.x; run[g + 4] = r;
            r += b4.y; run[g + 5] = r;
            r += b4.z; run[g + 6] = r;
            r += b4.w; run[g + 7] = r;
        }
        for (; g < N; ++g) { r += se[g]; run[g] = r; }
        float e0 = run[sB[1] - 1], e1 = run[sB[2] - 1], e2 = run[sB[3] - 1];
        float su0 = e0;             // sample_u = [end_u[0], end_u[2]-end_u[1], end_u[3]-end_u[2]]
        float su1 = e2 - e1;
        float su2 = run[sB[4] - 1] - e2;
        sCz[0] = 0.0f;
        sCz[1] = su0;
        sCz[2] = su0 + su1;
        sCz[3] = (su0 + su1) + su2;
    }
    __syncthreads();

    // ---- Phase C: parallel decisions (bit-identical per-element arithmetic) ----
    for (int g = tid; g < N; g += 256) {
        int seg = (g >= sB[1]) + (g >= sB[2]) + (g >= sB[3]);
        int st = (seg == 0) ? 0 : sB[seg];
        int qp1 = g - st + 1;
        float r2 = run[g] - sCz[seg];
        bool seld = (se[g] > r2 / (float)qp1) || (qp1 <= win);
        sFlag[g] = seld ? 1 : 0;
    }
    __syncthreads();

    // ---- Phase D: integer compaction (chunked scan, exact) ----
    int CH = (N + 255) >> 8;
    int lo = tid * CH, hi = min(lo + CH, N);
    {
        int s = 0;
        for (int g = lo; g < hi; ++g) s += sFlag[g];
        sSum[tid] = s;
    }
    __syncthreads();
    if (tid == 0) {
        int acc = 0;
        for (int t = 0; t < 256; ++t) { int v = sSum[t]; sSum[t] = acc; acc += v; }
    }
    __syncthreads();

    int* sel = (int*)(g_pool + selOff);
    int* tm  = (int*)(g_pool + tmOff);
    float* eus = g_pool + euSelOff;
    int* bn  = (int*)(g_pool + boundsNextOff);

    int csel0 = sFlag[0];            // g=0 always selected (qp1=1 <= win)
    {
        int csel = sSum[tid];        // exclusive base for this chunk
        for (int g = lo; g < hi; ++g) {
            csel += sFlag[g];
            tm[g] = csel - csel0;
            if (sFlag[g]) { sel[csel - 1] = g; eus[csel - 1] = se[g]; }
            #pragma unroll
            for (int s = 0; s < NBAT; ++s)
                if (g == sB[s + 1] - 1) sEc[s] = csel;
        }
    }
    __syncthreads();
    if (tid == 0) {
        bn[0] = 0; bn[1] = sEc[0]; bn[2] = sEc[1]; bn[3] = sEc[2]; bn[4] = sEc[3];
    }
}

// ---------------- r = softmax(gelu(h)@w2 + b2); dat[i] = sum_j r[j]*window(g,j) ----------------
__global__ __launch_bounds__(256) void k_rdat(
    size_t hOff, const float* __restrict__ w2, const float* __restrict__ b2,
    size_t selOff, size_t mdevOff,
    size_t srcOff, const float* __restrict__ buf, size_t boundsOff,
    size_t datOff)
{
    int i = blockIdx.x;
    if (i >= *(const int*)(g_pool + mdevOff)) return;
    const float* h = g_pool + hOff;
    const float* src = g_pool + srcOff;
    const int* bounds = (const int*)(g_pool + boundsOff);
    const int* sel = (const int*)(g_pool + selOff);
    float* dat = g_pool + datOff;

    __shared__ float gh[HID];
    __shared__ float sv[WSZ];
    __shared__ float r[WSZ];
    int tid = threadIdx.x;
    for (int k = tid; k < HID; k += 256) gh[k] = geluf(h[(size_t)i * HID + k]);
    __syncthreads();
    if (tid < WSZ) {
        float acc = 0.0f;
        for (int k = 0; k < HID; ++k) acc += gh[k] * w2[k * WSZ + tid];
        sv[tid] = acc + b2[tid];
    }
    __syncthreads();
    if (tid == 0) {
        float m = sv[0];
        for (int t = 1; t < WSZ; ++t) m = fmaxf(m, sv[t]);
        float sum = 0.0f;
        for (int t = 0; t < WSZ; ++t) { float e = expf(sv[t] - m); r[t] = e; sum += e; }
        for (int t = 0; t < WSZ; ++t) r[t] = r[t] / sum;
    }
    __syncthreads();
    int g = sel[i];
    int b1 = bounds[1], b2i = bounds[2], b3 = bounds[3];
    int s = (g >= b1) + (g >= b2i) + (g >= b3);
    int st = (s == 0) ? 0 : ((s == 1) ? b1 : ((s == 2) ? b2i : b3));
    int qp = g - st;
    for (int f = tid; f < F; f += 256) {
        float acc = 0.0f;
        for (int j = 0; j < WSZ; ++j) {
            int sp = qp - j;
            float v = (sp >= 0) ? src[(size_t)(g - j) * F + f]
                                : buf[(size_t)(15 + sp) * F + f];
            acc = fmaf(r[j], v, acc);
        }
        dat[(size_t)i * F + f] = acc;
    }
}

// ---------------- fused attention over 48 gathered kv slots ----------------
__global__ __launch_bounds__(512) void k_attn(
    const float* __restrict__ bk, const float* __restrict__ bv)
{
    int g = blockIdx.x;
    const float* qh   = g_pool + oQH;
    const float* KH0  = g_pool + oKH0;
    const float* VH0  = g_pool + oVH0;
    const float* BH0k = g_pool + oBH0K;
    const float* BH0v = g_pool + oBH0V;
    const float* DH1k = g_pool + oDH1K;
    const float* DH1v = g_pool + oDH1V;
    const float* DH2k = g_pool + oDH2K;
    const float* DH2v = g_pool + oDH2V;
    const float* eus0 = g_pool + oEUS0;
    const float* eus1 = g_pool + oEUS1;
    const int* tm0 = (const int*)(g_pool + oTM0);
    const int* tm1 = (const int*)(g_pool + oTM1);
    const int* bounds1 = (const int*)(g_pool + oB1);
    const int* bounds2 = (const int*)(g_pool + oB2);

    __shared__ const float* sK[48];
    __shared__ const float* sV[48];
    __shared__ float sScale[48];
    __shared__ float sQ[E], sBk[E], sBv[E];
    __shared__ float sc[48][8];

    int tid = threadIdx.x;
    sQ[tid]  = qh[(size_t)g * E + tid];
    sBk[tid] = bk[tid];
    sBv[tid] = bv[tid];

    if (tid < 48) {
        int s = tid;
        const float *pK = nullptr, *pV = nullptr;
        float scl = 0.0f;
        if (s < 16) {
            int s0 = (g >= 768) + (g >= 1408) + (g >= 2112);
            const int st0[4] = {0, 768, 1408, 2112};
            int sp = (g - st0[s0]) - s;
            if (sp >= 0) { pK = KH0 + (size_t)(g - s) * E; pV = VH0 + (size_t)(g - s) * E; }
            else         { pK = BH0k + (size_t)(15 + sp) * E; pV = BH0v + (size_t)(15 + sp) * E; }
            scl = 1.0f;
        } else if (s < 32) {
            int j = s - 16;
            int i1 = tm0[g];
            int b1 = bounds1[1], b2 = bounds1[2], b3 = bounds1[3];
            int sg = (i1 >= b1) + (i1 >= b2) + (i1 >= b3);
            int st = (sg == 0) ? 0 : ((sg == 1) ? b1 : ((sg == 2) ? b2 : b3));
            int sp = (i1 - st) - j;
            if (sp >= 0) { pK = DH1k + (size_t)(i1 - j) * E; pV = DH1v + (size_t)(i1 - j) * E; scl = eus0[i1 - j]; }
        } else {
            int j = s - 32;
            int i1 = tm0[g];
            int i2 = tm1[i1];
            int b1 = bounds2[1], b2 = bounds2[2], b3 = bounds2[3];
            int sg = (i2 >= b1) + (i2 >= b2) + (i2 >= b3);
            int st = (sg == 0) ? 0 : ((sg == 1) ? b1 : ((sg == 2) ? b2 : b3));
            int sp = (i2 - st) - j;
            if (sp >= 0) { pK = DH2k + (size_t)(i2 - j) * E; pV = DH2v + (size_t)(i2 - j) * E; scl = eus1[i2 - j]; }
        }
        sK[s] = pK; sV[s] = pV; sScale[s] = scl;
    }
    __syncthreads();

    if (tid < 384) {
        int s = tid >> 3, h = tid & 7;
        const float* bp = sK[s];
        float scl = sScale[s];
        float acc = 0.0f;
        int d0 = h * 64;
        if (s < 16) {
            for (int d = 0; d < 64; ++d) acc += sQ[d0 + d] * bp[d0 + d];  // bias baked in
        } else {
            for (int d = 0; d < 64; ++d) {
                float kvv = sBk[d0 + d] + (bp ? scl * bp[d0 + d] : 0.0f);
                acc += sQ[d0 + d] * kvv;
            }
        }
        sc[s][h] = acc * 0.125f;   // / sqrt(64)
    }
    __syncthreads();

    if (tid < 8) {
        int h = tid;
        float m = sc[0][h];
        for (int s = 1; s < 48; ++s) m = fmaxf(m, sc[s][h]);
        float sum = 0.0f;
        for (int s = 0; s < 48; ++s) { float e = expf(sc[s][h] - m); sc[s][h] = e; sum += e; }
        for (int s = 0; s < 48; ++s) sc[s][h] = sc[s][h] / sum;
    }
    __syncthreads();

    {
        int d = tid, h = d >> 6;
        float acc = 0.0f;
        for (int s = 0; s < 48; ++s) {
            const float* bp = sV[s];
            float vv;
            if (s < 16) vv = bp[d];
            else        vv = sBv[d] + (bp ? sScale[s] * bp[d] : 0.0f);
            acc = fmaf(sc[s][h], vv, acc);
        }
        g_pool[oCTX + (size_t)g * E + d] = acc;
    }
}

// ---------------- y2 -> out (B, 768, E) with zero padding ----------------
__global__ __launch_bounds__(256) void k_scatter(float* __restrict__ out) {
    int idx = blockIdx.x * 256 + threadIdx.x;
    if (idx >= NBAT * MAXL * E) return;
    int d = idx & (E - 1);
    int rest = idx >> 9;
    int p = rest % MAXL, bb = rest / MAXL;
    const int st[4] = {0, 768, 1408, 2112};
    const int ln[4] = {768, 640, 704, 600};
    out[idx] = (p < ln[bb]) ? g_pool[oY2 + (size_t)(st[bb] + p) * E + d] : 0.0f;
}

// ================================================================================
extern "C" void kernel_launch(void* const* d_in, const int* in_sizes, int n_in,
                              void* d_out, int out_size, void* d_ws, size_t ws_size,
                              hipStream_t stream)
{
    (void)in_sizes; (void)n_in; (void)d_ws; (void)ws_size; (void)out_size;

    const float* x      = (const float*)d_in[0];
    const float* kv_w   = (const float*)d_in[2];
    const float* kv_b   = (const float*)d_in[3];
    const float* q_w    = (const float*)d_in[4];
    const float* q_b    = (const float*)d_in[5];
    const float* proj_w = (const float*)d_in[6];
    const float* proj_b = (const float*)d_in[7];
    const float* buf0   = (const float*)d_in[8];
    const float* buf1   = (const float*)d_in[9];
    const float* d0_w1  = (const float*)d_in[11];
    const float* d0_b1  = (const float*)d_in[12];
    const float* d0_w2  = (const float*)d_in[13];
    const float* d0_b2  = (const float*)d_in[14];
    const float* u0_w1  = (const float*)d_in[15];
    const float* u0_b1  = (const float*)d_in[16];
    const float* u0_w2  = (const float*)d_in[17];
    const float* u0_b2  = (const float*)d_in[18];
    const float* d1_w1  = (const float*)d_in[19];
    const float* d1_b1  = (const float*)d_in[20];
    const float* d1_w2  = (const float*)d_in[21];
    const float* d1_b2  = (const float*)d_in[22];
    const float* u1_w1  = (const float*)d_in[23];
    const float* u1_b1  = (const float*)d_in[24];
    const float* u1_w2  = (const float*)d_in[25];
    const float* u1_b2  = (const float*)d_in[26];
    const float* wq     = (const float*)d_in[27];
    const float* bq     = (const float*)d_in[28];
    const float* wk     = (const float*)d_in[29];
    const float* bk     = (const float*)d_in[30];
    const float* wv     = (const float*)d_in[31];
    const float* bv     = (const float*)d_in[32];
    const float* out_w  = (const float*)d_in[33];
    const float* out_b  = (const float*)d_in[34];

    auto cdiv = [](int a, int b) { return (a + b - 1) / b; };
    auto G = [&](int M, int N) { return dim3(cdiv(M, 64), cdiv(N, 64)); };
    auto GT = [&](int M, int N) { return dim3(cdiv(M, 128), cdiv(N, 128)); };

    k_init<<<1, 64, 0, stream>>>();
    k_xflat<<<cdiv(N0 * E, 256), 256, 0, stream>>>(x);

    // weight prep: BD reshapes, combined wqc/wop
    k_reshape<<<cdiv(F * NY, 256), 256, 0, stream>>>(u0_w1, d0_w1, oBD0);
    k_reshape<<<cdiv(F * NY, 256), 256, 0, stream>>>(u1_w1, d1_w1, oBD1);
    k_pgemm<<<G(E, E), 256, 0, stream>>>(q_w, 0, E, wq, 0, nullptr, NOFF, oWQC, E, NOFF, E, E);
    k_vecmat<<<cdiv(E, 256), 256, 0, stream>>>(q_b, wq, bq, oBQC, E, E);
    k_pgemm<<<G(E, E), 256, 0, stream>>>(out_w, 0, E, proj_w, 0, nullptr, NOFF, oWOP, E, NOFF, E, E);
    k_vecmat<<<cdiv(E, 256), 256, 0, stream>>>(out_b, proj_w, proj_b, oBOP, E, E);

    // kv0 = x_flat @ kv_w + kv_b ; qh = x_flat @ wqc + bqc
    k_pgemm<<<G(N0, F), 256, 0, stream>>>(nullptr, oXF, E, kv_w, 0, kv_b, NOFF, oKV0, N0, NOFF, E, F);
    k_pgemm<<<G(N0, E), 256, 0, stream>>>(nullptr, oXF, E, nullptr, oWQC, nullptr, oBQC, oQH, N0, NOFF, E, E);

    // ---- level 0: Y = kv0 @ BD0 ; BufY0 = buf0 @ BD0 ----
    k_pgemm<<<G(15, NY), 256, 0, stream>>>(buf0, 0, F, nullptr, oBD0, nullptr, NOFF, oBUFY0, 15, NOFF, F, NY);
    k_tgemm<<<GT(N0, NY), 256, 0, stream>>>(oKV0, F, oBD0, oYB, N0, NOFF, F, NY);
    k_shiftsum<<<N0, 160, 0, stream>>>(0, NOFF, oB0, oBUFY0, u0_b1, oHU0, NOFF, N0);
    k_eu<<<N0, 64, 0, stream>>>(oHU0, u0_w2, u0_b2, oEU0, NOFF, N0);
    k_select<<<1, 256, 0, stream>>>(oEU0, oB0, WSZ, oSEL0, oTM0, oEUS0, oB1);

    // ---- d0 on selected rows -> dat1 ----
    k_shiftsum<<<N0, 160, 0, stream>>>(NY / 2, oSEL0, oB0, oBUFY0, d0_b1, oHD0, oB1 + 4, N0);
    k_rdat<<<N0, 256, 0, stream>>>(oHD0, d0_w2, d0_b2, oSEL0, oB1 + 4, oKV0, buf0, oB0, oDAT1);

    // ---- level 1: Y = dat1 @ BD1 (masked n1) ; BufY1 = buf1 @ BD1 ----
    k_pgemm<<<G(15, NY), 256, 0, stream>>>(buf1, 0, F, nullptr, oBD1, nullptr, NOFF, oBUFY1, 15, NOFF, F, NY);
    k_tgemm<<<GT(N0, NY), 256, 0, stream>>>(oDAT1, F, oBD1, oYB, N0, oB1 + 4, F, NY);
    k_shiftsum<<<N0, 160, 0, stream>>>(0, NOFF, oB1, oBUFY1, u1_b1, oHU1, oB1 + 4, N0);
    k_eu<<<N0, 64, 0, stream>>>(oHU1, u1_w2, u1_b2, oEU1, oB1 + 4, N0);
    k_select<<<1, 256, 0, stream>>>(oEU1, oB1, WSZ, oSEL1, oTM1, oEUS1, oB2);

    // ---- d1 on selected level-1 rows -> dat2 ----
    k_shiftsum<<<N0, 160, 0, stream>>>(NY / 2, oSEL1, oB1, oBUFY1, d1_b1, oHD1, oB2 + 4, N0);
    k_rdat<<<N0, 256, 0, stream>>>(oHD1, d1_w2, d1_b2, oSEL1, oB2 + 4, oDAT1, buf1, oB1, oDAT2);

    // ---- attention prep: project every distinct kv row once (linearity) ----
    k_pgemm<<<G(N0, E), 256, 0, stream>>>(nullptr, oKV0, F, wk, 0, bk, NOFF, oKH0, N0, NOFF, E, E);
    k_pgemm<<<G(N0, E), 256, 0, stream>>>(nullptr, oKV0 + E, F, wv, 0, bv, NOFF, oVH0, N0, NOFF, E, E);
    k_pgemm<<<G(15, E), 256, 0, stream>>>(buf0, 0, F, wk, 0, bk, NOFF, oBH0K, 15, NOFF, E, E);
    k_pgemm<<<G(15, E), 256, 0, stream>>>(buf0 + E, 0, F, wv, 0, bv, NOFF, oBH0V, 15, NOFF, E, E);
    k_pgemm<<<G(N0, E), 256, 0, stream>>>(nullptr, oDAT1, F, wk, 0, nullptr, NOFF, oDH1K, N0, oB1 + 4, E, E);
    k_pgemm<<<G(N0, E), 256, 0, stream>>>(nullptr, oDAT1 + E, F, wv, 0, nullptr, NOFF, oDH1V, N0, oB1 + 4, E, E);
    k_pgemm<<<G(N0, E), 256, 0, stream>>>(nullptr, oDAT2, F, wk, 0, nullptr, NOFF, oDH2K, N0, oB2 + 4, E, E);
    k_pgemm<<<G(N0, E), 256, 0, stream>>>(nullptr, oDAT2 + E, F, wv, 0, nullptr, NOFF, oDH2V, N0, oB2 + 4, E, E);

    // ---- fused attention + combined output projection + scatter ----
    k_attn<<<N0, 512, 0, stream>>>(bk, bv);
    k_pgemm<<<G(N0, E), 256, 0, stream>>>(nullptr, oCTX, E, nullptr, oWOP, nullptr, oBOP, oY2, N0, NOFF, E, E);
    k_scatter<<<cdiv(NBAT * MAXL * E, 256), 256, 0, stream>>>((float*)d_out);
}

// Round 5
// 2189.420 us; speedup vs baseline: 1.0846x; 1.0846x over previous
//
#include <hip/hip_runtime.h>
#include <cstddef>

#define DEVFN __device__ __forceinline__

constexpr int N0   = 2712;             // 768+640+704+600
constexpr int MAXL = 768;
constexpr int NBAT = 4;
constexpr int E    = 512;
constexpr int F    = 1024;
constexpr int HID  = 160;
constexpr int WSZ  = 16;               // window length
constexpr int NY   = 2 * WSZ * HID;    // 5120: [u | d] fused Y width
constexpr int XSTR = 2560;             // XO row: [kv0(1024) | KH0(512) | VH0(512) | qh(512)]
constexpr size_t NOFF = (size_t)-1;

// ---------------- static device scratch pool (offsets in floats) ----------------
constexpr size_t oXF    = 0;
constexpr size_t oXO    = oXF    + (size_t)N0*E;
constexpr size_t oHU0   = oXO    + (size_t)N0*XSTR;
constexpr size_t oEU0   = oHU0   + (size_t)N0*HID;
constexpr size_t oHD0   = oEU0   + (size_t)N0;
constexpr size_t oDAT1  = oHD0   + (size_t)N0*HID;
constexpr size_t oHU1   = oDAT1  + (size_t)N0*F;
constexpr size_t oEU1   = oHU1   + (size_t)N0*HID;
constexpr size_t oHD1   = oEU1   + (size_t)N0;
constexpr size_t oDAT2  = oHD1   + (size_t)N0*HID;
constexpr size_t oBH0K  = oDAT2  + (size_t)N0*F;
constexpr size_t oBH0V  = oBH0K  + (size_t)15*E;
constexpr size_t oDH1K  = oBH0V  + (size_t)15*E;   // DH1K,DH1V,DH2K,DH2V contiguous
constexpr size_t oDH1V  = oDH1K  + (size_t)N0*E;
constexpr size_t oDH2K  = oDH1V  + (size_t)N0*E;
constexpr size_t oDH2V  = oDH2K  + (size_t)N0*E;
constexpr size_t oCTX   = oDH2V  + (size_t)N0*E;
constexpr size_t oY2    = oCTX   + (size_t)N0*E;
constexpr size_t oEUS0  = oY2    + (size_t)N0*E;
constexpr size_t oEUS1  = oEUS0  + (size_t)N0;
constexpr size_t oSEL0  = oEUS1  + (size_t)N0;
constexpr size_t oTM0   = oSEL0  + (size_t)N0;
constexpr size_t oSEL1  = oTM0   + (size_t)N0;
constexpr size_t oTM1   = oSEL1  + (size_t)N0;
constexpr size_t oB0    = oTM1   + (size_t)N0;
constexpr size_t oB1    = oB0    + 8;
constexpr size_t oB2    = oB1    + 8;
constexpr size_t oWOP   = oB2    + 8;
constexpr size_t oBOP   = oWOP   + (size_t)E*E;
constexpr size_t oWX    = oBOP   + E;              // 512 x 2560
constexpr size_t oXB    = oWX    + (size_t)E*XSTR; // 2560 bias
constexpr size_t oBD0   = oXB    + XSTR;
constexpr size_t oBD1   = oBD0   + (size_t)F*NY;
constexpr size_t oBUFY0 = oBD1   + (size_t)F*NY;
constexpr size_t oBUFY1 = oBUFY0 + (size_t)15*NY;
constexpr size_t oYB    = oBUFY1 + (size_t)15*NY;
constexpr size_t oEND   = oYB    + (size_t)N0*NY;

__device__ float g_pool[oEND];

DEVFN float geluf(float x) {
    return 0.5f * x * (1.0f + erff(x / 1.41421356237309504880f));
}

// ---------------- tiny init ----------------
__global__ void k_init() {
    if (threadIdx.x == 0) {
        int* b = (int*)(g_pool + oB0);
        b[0] = 0; b[1] = 768; b[2] = 1408; b[3] = 2112; b[4] = N0;
    }
}

// ---------------- x (B,768,E) -> x_flat (N0,E) ----------------
__global__ __launch_bounds__(256) void k_xflat(const float* __restrict__ x) {
    int idx = blockIdx.x * 256 + threadIdx.x;
    if (idx >= N0 * E) return;
    int d = idx & (E - 1);
    int g = idx >> 9;
    int s = (g >= 768) + (g >= 1408) + (g >= 2112);
    const int st[4] = {0, 768, 1408, 2112};
    int qp = g - st[s];
    g_pool[oXF + idx] = x[((size_t)s * MAXL + qp) * E + d];
}

// ---------------- w1 (16384,160) pairs -> BD (1024, 5120) ----------------
__global__ __launch_bounds__(256) void k_reshape(
    const float* __restrict__ uw, const float* __restrict__ dw, size_t bdOff)
{
    int idx = blockIdx.x * 256 + threadIdx.x;
    if (idx >= F * NY) return;
    int col = idx % NY;
    int f = idx / NY;
    const float* src = (col < NY / 2) ? uw : dw;
    int rem = (col < NY / 2) ? col : col - NY / 2;
    int j = rem / HID, n = rem % HID;
    g_pool[bdOff + idx] = src[((size_t)j * F + f) * HID + n];
}

// ---------------- small copies ----------------
__global__ __launch_bounds__(256) void k_copymat(
    const float* __restrict__ src, size_t dstOff, int rows, int cols, int lds, int ldd)
{
    int idx = blockIdx.x * 256 + threadIdx.x;
    if (idx >= rows * cols) return;
    int r = idx / cols, c = idx % cols;
    g_pool[dstOff + (size_t)r * ldd + c] = src[(size_t)r * lds + c];
}
__global__ __launch_bounds__(256) void k_copyvec(const float* __restrict__ src, size_t dstOff, int n) {
    int i = blockIdx.x * 256 + threadIdx.x;
    if (i < n) g_pool[dstOff + i] = src[i];
}

// ---------------- out[n] = vec @ W + add ----------------
__global__ __launch_bounds__(256) void k_vecmat(
    const float* __restrict__ vec, const float* __restrict__ W,
    const float* __restrict__ add, size_t outOff, int K, int N)
{
    int n = blockIdx.x * 256 + threadIdx.x;
    if (n >= N) return;
    float s = add[n];
    for (int k = 0; k < K; ++k) s = fmaf(vec[k], W[(size_t)k * N + n], s);
    g_pool[outOff + n] = s;
}

// ---------------- plain f32 GEMM (64x64, 4x4): C = A@B + bias ----------------
__global__ __launch_bounds__(256) void k_pgemm(
    const float* __restrict__ Aext, size_t Aoff, int lda,
    const float* __restrict__ Bext, size_t Boff,
    const float* __restrict__ biasExt, size_t biasOff,
    size_t Coff, int ldc, int M, size_t mdevOff, int K, int N)
{
    int mval = (mdevOff == NOFF) ? M : *(const int*)(g_pool + mdevOff);
    int row0 = blockIdx.x * 64, col0 = blockIdx.y * 64;
    if (row0 >= mval) return;

    const float* A = Aext ? Aext : (g_pool + Aoff);
    const float* B = Bext ? Bext : (g_pool + Boff);
    const float* bias = biasExt ? biasExt : ((biasOff == NOFF) ? nullptr : g_pool + biasOff);
    float* C = g_pool + Coff;

    __shared__ __align__(16) float As[32][68];
    __shared__ __align__(16) float Bs[32][64];

    int tid = threadIdx.x;
    float acc[4][4] = {};
    int tx = tid & 15, ty = tid >> 4;

    for (int k0 = 0; k0 < K; k0 += 32) {
        #pragma unroll
        for (int l = 0; l < 8; ++l) {
            int idx = tid + l * 256;
            int kk = idx & 31, m = idx >> 5;
            int r = row0 + m;
            float v = 0.0f;
            if (r < mval) v = A[(size_t)r * lda + k0 + kk];
            As[kk][m] = v;
        }
        #pragma unroll
        for (int l = 0; l < 8; ++l) {
            int idx = tid + l * 256;
            int n = idx & 63, kk = idx >> 6;
            int col = col0 + n;
            float v = 0.0f;
            if (col < N) v = B[(size_t)(k0 + kk) * N + col];
            Bs[kk][n] = v;
        }
        __syncthreads();
        #pragma unroll
        for (int kk = 0; kk < 32; ++kk) {
            float4 a4 = *(const float4*)&As[kk][ty * 4];
            float4 b4 = *(const float4*)&Bs[kk][tx * 4];
            float av[4] = {a4.x, a4.y, a4.z, a4.w};
            float bv[4] = {b4.x, b4.y, b4.z, b4.w};
            #pragma unroll
            for (int i = 0; i < 4; ++i)
                #pragma unroll
                for (int jn = 0; jn < 4; ++jn)
                    acc[i][jn] = fmaf(av[i], bv[jn], acc[i][jn]);
        }
        __syncthreads();
    }

    #pragma unroll
    for (int i = 0; i < 4; ++i) {
        int r = row0 + ty * 4 + i;
        if (r >= mval) continue;
        #pragma unroll
        for (int jn = 0; jn < 4; ++jn) {
            int col = col0 + tx * 4 + jn;
            if (col < N)
                C[(size_t)r * ldc + col] = acc[i][jn] + (bias ? bias[col] : 0.0f);
        }
    }
}

// ---------------- 128x128 f32 GEMM body (8x8 micro, conflict-free B frags) ----------------
DEVFN void gemm128_body(
    const float* __restrict__ A, int lda,
    const float* __restrict__ B, int ldb,
    const float* __restrict__ bias,
    float* __restrict__ C, int ldc,
    int mval, int row0, int col0, int K)
{
    __shared__ __align__(16) float As[16][132];   // transposed: As[k][m]
    __shared__ __align__(16) float Bs[16][128];

    int tid = threadIdx.x;
    int tx = tid & 15, ty = tid >> 4;
    float acc[8][8] = {};

    for (int k0 = 0; k0 < K; k0 += 16) {
        #pragma unroll
        for (int l = 0; l < 2; ++l) {
            int idx = tid + l * 256;
            int r = idx >> 2, kq = (idx & 3) * 4;
            float4 v = make_float4(0.f, 0.f, 0.f, 0.f);
            int rr = row0 + r;
            if (rr < mval) v = *(const float4*)&A[(size_t)rr * lda + k0 + kq];
            As[kq][r] = v.x; As[kq + 1][r] = v.y; As[kq + 2][r] = v.z; As[kq + 3][r] = v.w;
        }
        #pragma unroll
        for (int l = 0; l < 2; ++l) {
            int idx = tid + l * 256;
            int k = idx >> 5, nq = (idx & 31) * 4;
            *(float4*)&Bs[k][nq] = *(const float4*)&B[(size_t)(k0 + k) * ldb + col0 + nq];
        }
        __syncthreads();
        #pragma unroll
        for (int kk = 0; kk < 16; ++kk) {
            float a0[8], b0[8];
            *(float4*)&a0[0] = *(const float4*)&As[kk][ty * 8];
            *(float4*)&a0[4] = *(const float4*)&As[kk][ty * 8 + 4];
            *(float4*)&b0[0] = *(const float4*)&Bs[kk][tx * 4];         // banks 0..31 x2: free
            *(float4*)&b0[4] = *(const float4*)&Bs[kk][64 + tx * 4];
            #pragma unroll
            for (int i = 0; i < 8; ++i)
                #pragma unroll
                for (int jn = 0; jn < 8; ++jn)
                    acc[i][jn] = fmaf(a0[i], b0[jn], acc[i][jn]);
        }
        __syncthreads();
    }

    #pragma unroll
    for (int i = 0; i < 8; ++i) {
        int r = row0 + ty * 8 + i;
        if (r >= mval) continue;
        float o0[4], o1[4];
        #pragma unroll
        for (int jn = 0; jn < 4; ++jn) {
            o0[jn] = acc[i][jn]     + (bias ? bias[col0 + tx * 4 + jn]      : 0.0f);
            o1[jn] = acc[i][jn + 4] + (bias ? bias[col0 + 64 + tx * 4 + jn] : 0.0f);
        }
        *(float4*)&C[(size_t)r * ldc + col0 + tx * 4]      = *(float4*)&o0[0];
        *(float4*)&C[(size_t)r * ldc + col0 + 64 + tx * 4] = *(float4*)&o1[0];
    }
}

__global__ __launch_bounds__(256) void k_tgemm(
    size_t Aoff, int lda, size_t Boff, int ldb, size_t biasOff,
    size_t Coff, int ldc, int M, size_t mdevOff, int K)
{
    int mval = (mdevOff == NOFF) ? M : *(const int*)(g_pool + mdevOff);
    int row0 = blockIdx.x * 128, col0 = blockIdx.y * 128;
    if (row0 >= mval) return;
    gemm128_body(g_pool + Aoff, lda, g_pool + Boff, ldb,
                 (biasOff == NOFF) ? nullptr : g_pool + biasOff,
                 g_pool + Coff, ldc, mval, row0, col0, K);
}

// z-batched DH projections: {dat1k@wk, dat1v@wv, dat2k@wk, dat2v@wv}
__global__ __launch_bounds__(256) void k_zgemm(
    const float* __restrict__ wk, const float* __restrict__ wv)
{
    int z = blockIdx.z;
    int mval = *(const int*)(g_pool + ((z < 2) ? (oB1 + 4) : (oB2 + 4)));
    int row0 = blockIdx.x * 128, col0 = blockIdx.y * 128;
    if (row0 >= mval) return;
    const float* A = g_pool + ((z < 2) ? oDAT1 : oDAT2) + (size_t)(z & 1) * E;
    const float* B = (z & 1) ? wv : wk;
    float* C = g_pool + oDH1K + (size_t)z * N0 * E;
    gemm128_body(A, F, B, E, nullptr, C, E, mval, row0, col0, E);
}

// ---------------- shift-sum epilogue ----------------
__global__ __launch_bounds__(160) void k_shiftsum(
    int colBase, size_t rowmapOff, size_t boundsOff, size_t bufYOff,
    const float* __restrict__ bias, size_t outOff, size_t mdevOff, int M)
{
    int i = blockIdx.x;
    int mval = (mdevOff == NOFF) ? M : *(const int*)(g_pool + mdevOff);
    if (i >= mval) return;
    int n = threadIdx.x;

    const int* bounds = (const int*)(g_pool + boundsOff);
    int g = (rowmapOff == NOFF) ? i : ((const int*)(g_pool + rowmapOff))[i];
    int b1 = bounds[1], b2 = bounds[2], b3 = bounds[3];
    int s = (g >= b1) + (g >= b2) + (g >= b3);
    int st = (s == 0) ? 0 : ((s == 1) ? b1 : ((s == 2) ? b2 : b3));
    int qp = g - st;

    const float* Y = g_pool + oYB;
    const float* bufY = g_pool + bufYOff;

    float acc = bias[n];
    #pragma unroll
    for (int j = 0; j < WSZ; ++j) {
        int sp = qp - j;
        const float* row = (sp >= 0) ? &Y[(size_t)(g - j) * NY]
                                     : &bufY[(size_t)(15 + sp) * NY];
        acc += row[colBase + j * HID + n];
    }
    g_pool[outOff + (size_t)i * HID + n] = acc;
}

// ---------------- eu = elu(gelu(h)@w2 + b2) + 1 ----------------
__global__ __launch_bounds__(64) void k_eu(
    size_t hOff, const float* __restrict__ w2, const float* __restrict__ b2,
    size_t euOff, size_t mdevOff, int M)
{
    int row = blockIdx.x;
    int mval = (mdevOff == NOFF) ? M : *(const int*)(g_pool + mdevOff);
    if (row >= mval) return;
    const float* h = g_pool + hOff;
    int lane = threadIdx.x;
    float s = 0.0f;
    for (int k = lane; k < HID; k += 64)
        s += geluf(h[(size_t)row * HID + k]) * w2[k];
    #pragma unroll
    for (int o = 32; o; o >>= 1) s += __shfl_xor(s, o, 64);
    if (lane == 0) {
        float v = s + b2[0];
        v = (v > 0.0f) ? v : expm1f(v);
        g_pool[euOff + row] = v + 1.0f;
    }
}

// ---------------- selection scan: serial f32 prefix (bit-exact) + parallel rest ----------------
__global__ __launch_bounds__(256) void k_select(
    size_t euOff, size_t boundsOff, int win,
    size_t selOff, size_t tmOff, size_t euSelOff, size_t boundsNextOff)
{
    __shared__ __align__(16) float se[N0];
    __shared__ __align__(16) float run[N0];
    __shared__ int sFlag[N0];
    __shared__ int sSum[256];
    __shared__ float sCz[NBAT];
    __shared__ int sEc[NBAT];
    __shared__ int sB[5];

    int tid = threadIdx.x;
    const int* bounds = (const int*)(g_pool + boundsOff);
    if (tid < 5) sB[tid] = bounds[tid];
    __syncthreads();
    int N = sB[4];
    for (int i = tid; i < N; i += 256) se[i] = g_pool[euOff + i];
    __syncthreads();

    if (tid == 0) {
        float r = 0.0f;
        int g = 0;
        for (; g + 8 <= N; g += 8) {
            float4 a = *(const float4*)&se[g];
            float4 b4 = *(const float4*)&se[g + 4];
            r += a.x;  run[g]     = r;
            r += a.y;  run[g + 1] = r;
            r += a.z;  run[g + 2] = r;
            r += a.w;  run[g + 3] = r;
            r += b4.x; run[g + 4] = r;
            r += b4.y; run[g + 5] = r;
            r += b4.z; run[g + 6] = r;
            r += b4.w; run[g + 7] = r;
        }
        for (; g < N; ++g) { r += se[g]; run[g] = r; }
        float e0 = run[sB[1] - 1], e1 = run[sB[2] - 1], e2 = run[sB[3] - 1];
        float su0 = e0;
        float su1 = e2 - e1;
        float su2 = run[sB[4] - 1] - e2;
        sCz[0] = 0.0f;
        sCz[1] = su0;
        sCz[2] = su0 + su1;
        sCz[3] = (su0 + su1) + su2;
    }
    __syncthreads();

    for (int g = tid; g < N; g += 256) {
        int seg = (g >= sB[1]) + (g >= sB[2]) + (g >= sB[3]);
        int st = (seg == 0) ? 0 : sB[seg];
        int qp1 = g - st + 1;
        float r2 = run[g] - sCz[seg];
        bool seld = (se[g] > r2 / (float)qp1) || (qp1 <= win);
        sFlag[g] = seld ? 1 : 0;
    }
    __syncthreads();

    int CH = (N + 255) >> 8;
    int lo = tid * CH, hi = min(lo + CH, N);
    {
        int s = 0;
        for (int g = lo; g < hi; ++g) s += sFlag[g];
        sSum[tid] = s;
    }
    __syncthreads();
    if (tid == 0) {
        int acc = 0;
        for (int t = 0; t < 256; ++t) { int v = sSum[t]; sSum[t] = acc; acc += v; }
    }
    __syncthreads();

    int* sel = (int*)(g_pool + selOff);
    int* tm  = (int*)(g_pool + tmOff);
    float* eus = g_pool + euSelOff;
    int* bn  = (int*)(g_pool + boundsNextOff);

    int csel0 = sFlag[0];
    {
        int csel = sSum[tid];
        for (int g = lo; g < hi; ++g) {
            csel += sFlag[g];
            tm[g] = csel - csel0;
            if (sFlag[g]) { sel[csel - 1] = g; eus[csel - 1] = se[g]; }
            #pragma unroll
            for (int s = 0; s < NBAT; ++s)
                if (g == sB[s + 1] - 1) sEc[s] = csel;
        }
    }
    __syncthreads();
    if (tid == 0) {
        bn[0] = 0; bn[1] = sEc[0]; bn[2] = sEc[1]; bn[3] = sEc[2]; bn[4] = sEc[3];
    }
}

// ---------------- r = softmax(gelu(h)@w2 + b2); dat[i] = sum_j r[j]*window(g,j) ----------------
__global__ __launch_bounds__(256) void k_rdat(
    size_t hOff, const float* __restrict__ w2, const float* __restrict__ b2,
    size_t selOff, size_t mdevOff,
    size_t srcOff, int srcStr, const float* __restrict__ buf, size_t boundsOff,
    size_t datOff)
{
    int i = blockIdx.x;
    if (i >= *(const int*)(g_pool + mdevOff)) return;
    const float* h = g_pool + hOff;
    const float* src = g_pool + srcOff;
    const int* bounds = (const int*)(g_pool + boundsOff);
    const int* sel = (const int*)(g_pool + selOff);
    float* dat = g_pool + datOff;

    __shared__ float gh[HID];
    __shared__ float sv[WSZ];
    __shared__ float r[WSZ];
    int tid = threadIdx.x;
    for (int k = tid; k < HID; k += 256) gh[k] = geluf(h[(size_t)i * HID + k]);
    __syncthreads();
    if (tid < WSZ) {
        float acc = 0.0f;
        for (int k = 0; k < HID; ++k) acc += gh[k] * w2[k * WSZ + tid];
        sv[tid] = acc + b2[tid];
    }
    __syncthreads();
    if (tid == 0) {
        float m = sv[0];
        for (int t = 1; t < WSZ; ++t) m = fmaxf(m, sv[t]);
        float sum = 0.0f;
        for (int t = 0; t < WSZ; ++t) { float e = expf(sv[t] - m); r[t] = e; sum += e; }
        for (int t = 0; t < WSZ; ++t) r[t] = r[t] / sum;
    }
    __syncthreads();
    int g = sel[i];
    int b1 = bounds[1], b2i = bounds[2], b3 = bounds[3];
    int s = (g >= b1) + (g >= b2i) + (g >= b3);
    int st = (s == 0) ? 0 : ((s == 1) ? b1 : ((s == 2) ? b2i : b3));
    int qp = g - st;
    for (int f = tid; f < F; f += 256) {
        float acc = 0.0f;
        for (int j = 0; j < WSZ; ++j) {
            int sp = qp - j;
            float v = (sp >= 0) ? src[(size_t)(g - j) * srcStr + f]
                                : buf[(size_t)(15 + sp) * F + f];
            acc = fmaf(r[j], v, acc);
        }
        dat[(size_t)i * F + f] = acc;
    }
}

// ---------------- fused attention over 48 gathered kv slots ----------------
__global__ __launch_bounds__(512) void k_attn(
    const float* __restrict__ bk, const float* __restrict__ bv)
{
    int g = blockIdx.x;
    const float* XO   = g_pool + oXO;
    const float* BH0k = g_pool + oBH0K;
    const float* BH0v = g_pool + oBH0V;
    const float* DH1k = g_pool + oDH1K;
    const float* DH1v = g_pool + oDH1V;
    const float* DH2k = g_pool + oDH2K;
    const float* DH2v = g_pool + oDH2V;
    const float* eus0 = g_pool + oEUS0;
    const float* eus1 = g_pool + oEUS1;
    const int* tm0 = (const int*)(g_pool + oTM0);
    const int* tm1 = (const int*)(g_pool + oTM1);
    const int* bounds1 = (const int*)(g_pool + oB1);
    const int* bounds2 = (const int*)(g_pool + oB2);

    __shared__ const float* sK[48];
    __shared__ const float* sV[48];
    __shared__ float sScale[48];
    __shared__ float sQ[E], sBk[E], sBv[E];
    __shared__ float sc[48][8];

    int tid = threadIdx.x;
    sQ[tid]  = XO[(size_t)g * XSTR + 2048 + tid];
    sBk[tid] = bk[tid];
    sBv[tid] = bv[tid];

    if (tid < 48) {
        int s = tid;
        const float *pK = nullptr, *pV = nullptr;
        float scl = 0.0f;
        if (s < 16) {
            int s0 = (g >= 768) + (g >= 1408) + (g >= 2112);
            const int st0[4] = {0, 768, 1408, 2112};
            int sp = (g - st0[s0]) - s;
            if (sp >= 0) { pK = XO + (size_t)(g - s) * XSTR + 1024; pV = XO + (size_t)(g - s) * XSTR + 1536; }
            else         { pK = BH0k + (size_t)(15 + sp) * E; pV = BH0v + (size_t)(15 + sp) * E; }
            scl = 1.0f;
        } else if (s < 32) {
            int j = s - 16;
            int i1 = tm0[g];
            int b1 = bounds1[1], b2 = bounds1[2], b3 = bounds1[3];
            int sg = (i1 >= b1) + (i1 >= b2) + (i1 >= b3);
            int st = (sg == 0) ? 0 : ((sg == 1) ? b1 : ((sg == 2) ? b2 : b3));
            int sp = (i1 - st) - j;
            if (sp >= 0) { pK = DH1k + (size_t)(i1 - j) * E; pV = DH1v + (size_t)(i1 - j) * E; scl = eus0[i1 - j]; }
        } else {
            int j = s - 32;
            int i1 = tm0[g];
            int i2 = tm1[i1];
            int b1 = bounds2[1], b2 = bounds2[2], b3 = bounds2[3];
            int sg = (i2 >= b1) + (i2 >= b2) + (i2 >= b3);
            int st = (sg == 0) ? 0 : ((sg == 1) ? b1 : ((sg == 2) ? b2 : b3));
            int sp = (i2 - st) - j;
            if (sp >= 0) { pK = DH2k + (size_t)(i2 - j) * E; pV = DH2v + (size_t)(i2 - j) * E; scl = eus1[i2 - j]; }
        }
        sK[s] = pK; sV[s] = pV; sScale[s] = scl;
    }
    __syncthreads();

    if (tid < 384) {
        int s = tid >> 3, h = tid & 7;
        const float* bp = sK[s];
        float scl = sScale[s];
        float acc = 0.0f;
        int d0 = h * 64;
        if (s < 16) {
            for (int d = 0; d < 64; ++d) acc += sQ[d0 + d] * bp[d0 + d];  // bias baked in
        } else {
            for (int d = 0; d < 64; ++d) {
                float kvv = sBk[d0 + d] + (bp ? scl * bp[d0 + d] : 0.0f);
                acc += sQ[d0 + d] * kvv;
            }
        }
        sc[s][h] = acc * 0.125f;   // / sqrt(64)
    }
    __syncthreads();

    if (tid < 8) {
        int h = tid;
        float m = sc[0][h];
        for (int s = 1; s < 48; ++s) m = fmaxf(m, sc[s][h]);
        float sum = 0.0f;
        for (int s = 0; s < 48; ++s) { float e = expf(sc[s][h] - m); sc[s][h] = e; sum += e; }
        for (int s = 0; s < 48; ++s) sc[s][h] = sc[s][h] / sum;
    }
    __syncthreads();

    {
        int d = tid, h = d >> 6;
        float acc = 0.0f;
        for (int s = 0; s < 48; ++s) {
            const float* bp = sV[s];
            float vv;
            if (s < 16) vv = bp[d];
            else        vv = sBv[d] + (bp ? sScale[s] * bp[d] : 0.0f);
            acc = fmaf(sc[s][h], vv, acc);
        }
        g_pool[oCTX + (size_t)g * E + d] = acc;
    }
}

// ---------------- y2 -> out (B, 768, E) with zero padding ----------------
__global__ __launch_bounds__(256) void k_scatter(float* __restrict__ out) {
    int idx = blockIdx.x * 256 + threadIdx.x;
    if (idx >= NBAT * MAXL * E) return;
    int d = idx & (E - 1);
    int rest = idx >> 9;
    int p = rest % MAXL, bb = rest / MAXL;
    const int st[4] = {0, 768, 1408, 2112};
    const int ln[4] = {768, 640, 704, 600};
    out[idx] = (p < ln[bb]) ? g_pool[oY2 + (size_t)(st[bb] + p) * E + d] : 0.0f;
}

// ================================================================================
extern "C" void kernel_launch(void* const* d_in, const int* in_sizes, int n_in,
                              void* d_out, int out_size, void* d_ws, size_t ws_size,
                              hipStream_t stream)
{
    (void)in_sizes; (void)n_in; (void)d_ws; (void)ws_size; (void)out_size;

    const float* x      = (const float*)d_in[0];
    const float* kv_w   = (const float*)d_in[2];
    const float* kv_b   = (const float*)d_in[3];
    const float* q_w    = (const float*)d_in[4];
    const float* q_b    = (const float*)d_in[5];
    const float* proj_w = (const float*)d_in[6];
    const float* proj_b = (const float*)d_in[7];
    const float* buf0   = (const float*)d_in[8];
    const float* buf1   = (const float*)d_in[9];
    const float* d0_w1  = (const float*)d_in[11];
    const float* d0_b1  = (const float*)d_in[12];
    const float* d0_w2  = (const float*)d_in[13];
    const float* d0_b2  = (const float*)d_in[14];
    const float* u0_w1  = (const float*)d_in[15];
    const float* u0_b1  = (const float*)d_in[16];
    const float* u0_w2  = (const float*)d_in[17];
    const float* u0_b2  = (const float*)d_in[18];
    const float* d1_w1  = (const float*)d_in[19];
    const float* d1_b1  = (const float*)d_in[20];
    const float* d1_w2  = (const float*)d_in[21];
    const float* d1_b2  = (const float*)d_in[22];
    const float* u1_w1  = (const float*)d_in[23];
    const float* u1_b1  = (const float*)d_in[24];
    const float* u1_w2  = (const float*)d_in[25];
    const float* u1_b2  = (const float*)d_in[26];
    const float* wq     = (const float*)d_in[27];
    const float* bq     = (const float*)d_in[28];
    const float* wk     = (const float*)d_in[29];
    const float* bk     = (const float*)d_in[30];
    const float* wv     = (const float*)d_in[31];
    const float* bv     = (const float*)d_in[32];
    const float* out_w  = (const float*)d_in[33];
    const float* out_b  = (const float*)d_in[34];

    auto cdiv = [](int a, int b) { return (a + b - 1) / b; };
    auto G = [&](int M, int N) { return dim3(cdiv(M, 64), cdiv(N, 64)); };
    auto GT = [&](int M, int N) { return dim3(cdiv(M, 128), cdiv(N, 128)); };

    k_init<<<1, 64, 0, stream>>>();
    k_xflat<<<cdiv(N0 * E, 256), 256, 0, stream>>>(x);

    // ---- weight prep ----
    k_reshape<<<cdiv(F * NY, 256), 256, 0, stream>>>(u0_w1, d0_w1, oBD0);
    k_reshape<<<cdiv(F * NY, 256), 256, 0, stream>>>(u1_w1, d1_w1, oBD1);
    // WX = [kv_w | kv_w_k@wk | kv_w_v@wv | q_w@wq], XB = [kv_b | bkc | bvc | bqc]
    k_copymat<<<cdiv(E * F, 256), 256, 0, stream>>>(kv_w, oWX, E, F, F, XSTR);
    k_pgemm<<<G(E, E), 256, 0, stream>>>(kv_w, 0, F, wk, 0, nullptr, NOFF, oWX + 1024, XSTR, E, NOFF, E, E);
    k_pgemm<<<G(E, E), 256, 0, stream>>>(kv_w + E, 0, F, wv, 0, nullptr, NOFF, oWX + 1536, XSTR, E, NOFF, E, E);
    k_pgemm<<<G(E, E), 256, 0, stream>>>(q_w, 0, E, wq, 0, nullptr, NOFF, oWX + 2048, XSTR, E, NOFF, E, E);
    k_copyvec<<<cdiv(F, 256), 256, 0, stream>>>(kv_b, oXB, F);
    k_vecmat<<<cdiv(E, 256), 256, 0, stream>>>(kv_b, wk, bk, oXB + 1024, E, E);
    k_vecmat<<<cdiv(E, 256), 256, 0, stream>>>(kv_b + E, wv, bv, oXB + 1536, E, E);
    k_vecmat<<<cdiv(E, 256), 256, 0, stream>>>(q_b, wq, bq, oXB + 2048, E, E);
    k_pgemm<<<G(E, E), 256, 0, stream>>>(out_w, 0, E, proj_w, 0, nullptr, NOFF, oWOP, E, E, NOFF, E, E);
    k_vecmat<<<cdiv(E, 256), 256, 0, stream>>>(out_b, proj_w, proj_b, oBOP, E, E);

    // ---- X-GEMM: XO = xf @ WX + XB  -> [kv0 | KH0 | VH0 | qh] ----
    k_tgemm<<<GT(N0, XSTR), 256, 0, stream>>>(oXF, E, oWX, XSTR, oXB, oXO, XSTR, N0, NOFF, E);

    // ---- level 0 ----
    k_pgemm<<<G(15, NY), 256, 0, stream>>>(buf0, 0, F, nullptr, oBD0, nullptr, NOFF, oBUFY0, NY, 15, NOFF, F, NY);
    k_tgemm<<<GT(N0, NY), 256, 0, stream>>>(oXO, XSTR, oBD0, NY, NOFF, oYB, NY, N0, NOFF, F);
    k_shiftsum<<<N0, 160, 0, stream>>>(0, NOFF, oB0, oBUFY0, u0_b1, oHU0, NOFF, N0);
    k_eu<<<N0, 64, 0, stream>>>(oHU0, u0_w2, u0_b2, oEU0, NOFF, N0);
    k_select<<<1, 256, 0, stream>>>(oEU0, oB0, WSZ, oSEL0, oTM0, oEUS0, oB1);

    // ---- d0 -> dat1 ----
    k_shiftsum<<<N0, 160, 0, stream>>>(NY / 2, oSEL0, oB0, oBUFY0, d0_b1, oHD0, oB1 + 4, N0);
    k_rdat<<<N0, 256, 0, stream>>>(oHD0, d0_w2, d0_b2, oSEL0, oB1 + 4, oXO, XSTR, buf0, oB0, oDAT1);

    // ---- level 1 ----
    k_pgemm<<<G(15, NY), 256, 0, stream>>>(buf1, 0, F, nullptr, oBD1, nullptr, NOFF, oBUFY1, NY, 15, NOFF, F, NY);
    k_tgemm<<<GT(N0, NY), 256, 0, stream>>>(oDAT1, F, oBD1, NY, NOFF, oYB, NY, N0, oB1 + 4, F);
    k_shiftsum<<<N0, 160, 0, stream>>>(0, NOFF, oB1, oBUFY1, u1_b1, oHU1, oB1 + 4, N0);
    k_eu<<<N0, 64, 0, stream>>>(oHU1, u1_w2, u1_b2, oEU1, oB1 + 4, N0);
    k_select<<<1, 256, 0, stream>>>(oEU1, oB1, WSZ, oSEL1, oTM1, oEUS1, oB2);

    // ---- d1 -> dat2 ----
    k_shiftsum<<<N0, 160, 0, stream>>>(NY / 2, oSEL1, oB1, oBUFY1, d1_b1, oHD1, oB2 + 4, N0);
    k_rdat<<<N0, 256, 0, stream>>>(oHD1, d1_w2, d1_b2, oSEL1, oB2 + 4, oDAT1, F, buf1, oB1, oDAT2);

    // ---- DH projections (z-batched) + buffer projections ----
    k_zgemm<<<dim3(cdiv(N0, 128), 4, 4), 256, 0, stream>>>(wk, wv);
    k_pgemm<<<G(15, E), 256, 0, stream>>>(buf0, 0, F, wk, 0, bk, NOFF, oBH0K, E, 15, NOFF, E, E);
    k_pgemm<<<G(15, E), 256, 0, stream>>>(buf0 + E, 0, F, wv, 0, bv, NOFF, oBH0V, E, 15, NOFF, E, E);

    // ---- fused attention + combined output projection + scatter ----
    k_attn<<<N0, 512, 0, stream>>>(bk, bv);
    k_pgemm<<<G(N0, E), 256, 0, stream>>>(nullptr, oCTX, E, nullptr, oWOP, nullptr, oBOP, oY2, E, N0, NOFF, E, E);
    k_scatter<<<cdiv(NBAT * MAXL * E, 256), 256, 0, stream>>>((float*)d_out);
}

// Round 6
// 1561.712 us; speedup vs baseline: 1.5205x; 1.4019x over previous
//
#include <hip/hip_runtime.h>
#include <cstddef>

#define DEVFN __device__ __forceinline__

constexpr int N0   = 2712;             // 768+640+704+600
constexpr int MAXL = 768;
constexpr int NBAT = 4;
constexpr int E    = 512;
constexpr int F    = 1024;
constexpr int HID  = 160;
constexpr int WSZ  = 16;               // window length
constexpr int NY   = 2 * WSZ * HID;    // 5120: [u | d] fused Y width
constexpr int XSTR = 2560;             // XO row: [kv0(1024) | KH0(512) | VH0(512) | qh(512)]
constexpr size_t NOFF = (size_t)-1;

// ---------------- static device scratch pool (offsets in floats) ----------------
constexpr size_t oXF    = 0;
constexpr size_t oXO    = oXF    + (size_t)N0*E;
constexpr size_t oEU0   = oXO    + (size_t)N0*XSTR;
constexpr size_t oDAT1  = oEU0   + (size_t)N0;
constexpr size_t oEU1   = oDAT1  + (size_t)N0*F;
constexpr size_t oDAT2  = oEU1   + (size_t)N0;
constexpr size_t oBH0K  = oDAT2  + (size_t)N0*F;
constexpr size_t oBH0V  = oBH0K  + (size_t)15*E;
constexpr size_t oDH1K  = oBH0V  + (size_t)15*E;   // DH1K,DH1V,DH2K,DH2V contiguous
constexpr size_t oDH1V  = oDH1K  + (size_t)N0*E;
constexpr size_t oDH2K  = oDH1V  + (size_t)N0*E;
constexpr size_t oDH2V  = oDH2K  + (size_t)N0*E;
constexpr size_t oCTX   = oDH2V  + (size_t)N0*E;
constexpr size_t oY2    = oCTX   + (size_t)N0*E;
constexpr size_t oEUS0  = oY2    + (size_t)N0*E;
constexpr size_t oEUS1  = oEUS0  + (size_t)N0;
constexpr size_t oSEL0  = oEUS1  + (size_t)N0;
constexpr size_t oTM0   = oSEL0  + (size_t)N0;
constexpr size_t oSEL1  = oTM0   + (size_t)N0;
constexpr size_t oTM1   = oSEL1  + (size_t)N0;
constexpr size_t oB0    = oTM1   + (size_t)N0;
constexpr size_t oB1    = oB0    + 8;
constexpr size_t oB2    = oB1    + 8;
constexpr size_t oWOP   = oB2    + 8;
constexpr size_t oBOP   = oWOP   + (size_t)E*E;
constexpr size_t oWX    = oBOP   + E;              // 512 x 2560
constexpr size_t oXB    = oWX    + (size_t)E*XSTR; // 2560 bias
constexpr size_t oBD0   = oXB    + XSTR;
constexpr size_t oBD1   = oBD0   + (size_t)F*NY;
constexpr size_t oBUFY0 = oBD1   + (size_t)F*NY;
constexpr size_t oBUFY1 = oBUFY0 + (size_t)15*NY;
constexpr size_t oYB    = oBUFY1 + (size_t)15*NY;
constexpr size_t oEND   = oYB    + (size_t)N0*NY;

__device__ float g_pool[oEND];

DEVFN float geluf(float x) {
    return 0.5f * x * (1.0f + erff(x / 1.41421356237309504880f));
}

// ---------------- tiny init ----------------
__global__ void k_init() {
    if (threadIdx.x == 0) {
        int* b = (int*)(g_pool + oB0);
        b[0] = 0; b[1] = 768; b[2] = 1408; b[3] = 2112; b[4] = N0;
    }
}

// ---------------- x (B,768,E) -> x_flat (N0,E) ----------------
__global__ __launch_bounds__(256) void k_xflat(const float* __restrict__ x) {
    int idx = blockIdx.x * 256 + threadIdx.x;
    if (idx >= N0 * E) return;
    int d = idx & (E - 1);
    int g = idx >> 9;
    int s = (g >= 768) + (g >= 1408) + (g >= 2112);
    const int st[4] = {0, 768, 1408, 2112};
    int qp = g - st[s];
    g_pool[oXF + idx] = x[((size_t)s * MAXL + qp) * E + d];
}

// ---------------- w1 (16384,160) pairs -> BD (1024, 5120) ----------------
__global__ __launch_bounds__(256) void k_reshape(
    const float* __restrict__ uw, const float* __restrict__ dw, size_t bdOff)
{
    int idx = blockIdx.x * 256 + threadIdx.x;
    if (idx >= F * NY) return;
    int col = idx % NY;
    int f = idx / NY;
    const float* src = (col < NY / 2) ? uw : dw;
    int rem = (col < NY / 2) ? col : col - NY / 2;
    int j = rem / HID, n = rem % HID;
    g_pool[bdOff + idx] = src[((size_t)j * F + f) * HID + n];
}

// ---------------- kv_w -> WX[:, 0:1024] ----------------
__global__ __launch_bounds__(256) void k_copymat(
    const float* __restrict__ src, size_t dstOff, int rows, int cols, int lds, int ldd)
{
    int idx = blockIdx.x * 256 + threadIdx.x;
    if (idx >= rows * cols) return;
    int r = idx / cols, c = idx % cols;
    g_pool[dstOff + (size_t)r * ldd + c] = src[(size_t)r * lds + c];
}

// ---------------- fused bias prep: XB[2560] + BOP[512] ----------------
__global__ __launch_bounds__(256) void k_prepvec(
    const float* __restrict__ kv_b, const float* __restrict__ q_b, const float* __restrict__ out_b,
    const float* __restrict__ wk, const float* __restrict__ bk,
    const float* __restrict__ wv, const float* __restrict__ bv,
    const float* __restrict__ wq, const float* __restrict__ bq,
    const float* __restrict__ proj_w, const float* __restrict__ proj_b)
{
    int idx = blockIdx.x * 256 + threadIdx.x;
    if (idx >= 3072) return;
    if (idx < 1024) { g_pool[oXB + idx] = kv_b[idx]; return; }
    const float* vec; const float* W; const float* add; int n; size_t dst;
    if (idx < 1536)      { n = idx - 1024; vec = kv_b;     W = wk;     add = bk;     dst = oXB + idx; }
    else if (idx < 2048) { n = idx - 1536; vec = kv_b + E; W = wv;     add = bv;     dst = oXB + idx; }
    else if (idx < 2560) { n = idx - 2048; vec = q_b;      W = wq;     add = bq;     dst = oXB + idx; }
    else                 { n = idx - 2560; vec = out_b;    W = proj_w; add = proj_b; dst = oBOP + n; }
    float s = add[n];
    for (int k = 0; k < E; ++k) s = fmaf(vec[k], W[(size_t)k * E + n], s);
    g_pool[dst] = s;
}

// ---------------- 64x64 f32 GEMM body (4x4 micro, 256 threads) ----------------
DEVFN void gemm64_body(
    const float* __restrict__ A, int lda,
    const float* __restrict__ B, int ldb,
    const float* __restrict__ bias,
    float* __restrict__ C, int ldc,
    int mval, int row0, int col0, int K, int N)
{
    __shared__ __align__(16) float As[32][68];
    __shared__ __align__(16) float Bs[32][64];

    int tid = threadIdx.x;
    float acc[4][4] = {};
    int tx = tid & 15, ty = tid >> 4;

    for (int k0 = 0; k0 < K; k0 += 32) {
        #pragma unroll
        for (int l = 0; l < 8; ++l) {
            int idx = tid + l * 256;
            int kk = idx & 31, m = idx >> 5;
            int r = row0 + m;
            float v = 0.0f;
            if (r < mval) v = A[(size_t)r * lda + k0 + kk];
            As[kk][m] = v;
        }
        #pragma unroll
        for (int l = 0; l < 8; ++l) {
            int idx = tid + l * 256;
            int n = idx & 63, kk = idx >> 6;
            int col = col0 + n;
            float v = 0.0f;
            if (col < N) v = B[(size_t)(k0 + kk) * ldb + col];
            Bs[kk][n] = v;
        }
        __syncthreads();
        #pragma unroll
        for (int kk = 0; kk < 32; ++kk) {
            float4 a4 = *(const float4*)&As[kk][ty * 4];
            float4 b4 = *(const float4*)&Bs[kk][tx * 4];
            float av[4] = {a4.x, a4.y, a4.z, a4.w};
            float bv[4] = {b4.x, b4.y, b4.z, b4.w};
            #pragma unroll
            for (int i = 0; i < 4; ++i)
                #pragma unroll
                for (int jn = 0; jn < 4; ++jn)
                    acc[i][jn] = fmaf(av[i], bv[jn], acc[i][jn]);
        }
        __syncthreads();
    }

    #pragma unroll
    for (int i = 0; i < 4; ++i) {
        int r = row0 + ty * 4 + i;
        if (r >= mval) continue;
        #pragma unroll
        for (int jn = 0; jn < 4; ++jn) {
            int col = col0 + tx * 4 + jn;
            if (col < N)
                C[(size_t)r * ldc + col] = acc[i][jn] + (bias ? bias[col] : 0.0f);
        }
    }
}

// generic pool-based 64-tile GEMM (y2 projection)
__global__ __launch_bounds__(256) void k_pgemm(
    size_t Aoff, int lda, size_t Boff, int ldb, size_t biasOff,
    size_t Coff, int ldc, int M, size_t mdevOff, int K, int N)
{
    int mval = (mdevOff == NOFF) ? M : *(const int*)(g_pool + mdevOff);
    int row0 = blockIdx.x * 64, col0 = blockIdx.y * 64;
    if (row0 >= mval) return;
    gemm64_body(g_pool + Aoff, lda, g_pool + Boff, ldb,
                (biasOff == NOFF) ? nullptr : g_pool + biasOff,
                g_pool + Coff, ldc, mval, row0, col0, K, N);
}

// z-batched weight-prep: {kv_w_k@wk, kv_w_v@wv, q_w@wq, out_w@proj_w}
__global__ __launch_bounds__(256) void k_wprep(
    const float* __restrict__ kv_w, const float* __restrict__ q_w, const float* __restrict__ out_w,
    const float* __restrict__ wk, const float* __restrict__ wv,
    const float* __restrict__ wq, const float* __restrict__ proj_w)
{
    int z = blockIdx.z;
    const float* A; int lda; const float* B; float* C; int ldc;
    if (z == 0)      { A = kv_w;     lda = F; B = wk;     C = g_pool + oWX + 1024; ldc = XSTR; }
    else if (z == 1) { A = kv_w + E; lda = F; B = wv;     C = g_pool + oWX + 1536; ldc = XSTR; }
    else if (z == 2) { A = q_w;      lda = E; B = wq;     C = g_pool + oWX + 2048; ldc = XSTR; }
    else             { A = out_w;    lda = E; B = proj_w; C = g_pool + oWOP;       ldc = E;    }
    gemm64_body(A, lda, B, E, nullptr, C, ldc, E, blockIdx.x * 64, blockIdx.y * 64, E, E);
}

// z-batched bufY: {buf0@BD0, buf1@BD1}
__global__ __launch_bounds__(256) void k_bufy(
    const float* __restrict__ buf0, const float* __restrict__ buf1)
{
    int z = blockIdx.z;
    const float* A = z ? buf1 : buf0;
    const float* B = g_pool + (z ? oBD1 : oBD0);
    float* C = g_pool + (z ? oBUFY1 : oBUFY0);
    gemm64_body(A, F, B, NY, nullptr, C, NY, 15, 0, blockIdx.y * 64, F, NY);
}

// z-batched buffer K/V projections: {buf0_k@wk+bk, buf0_v@wv+bv}
__global__ __launch_bounds__(256) void k_bh(
    const float* __restrict__ buf0,
    const float* __restrict__ wk, const float* __restrict__ bk,
    const float* __restrict__ wv, const float* __restrict__ bv)
{
    int z = blockIdx.z;
    const float* A = buf0 + (size_t)z * E;
    const float* B = z ? wv : wk;
    const float* bias = z ? bv : bk;
    float* C = g_pool + (z ? oBH0V : oBH0K);
    gemm64_body(A, F, B, E, bias, C, E, 15, 0, blockIdx.y * 64, E, E);
}

// ---------------- big f32 GEMM: 128x128 tile, 128 threads, 16x8 micro ----------------
DEVFN void gemm128_body(
    const float* __restrict__ A, int lda,
    const float* __restrict__ B, int ldb,
    const float* __restrict__ bias,
    float* __restrict__ C, int ldc,
    int mval, int row0, int col0, int K)
{
    __shared__ __align__(16) float As[16][132];   // transposed: As[k][m]
    __shared__ __align__(16) float Bs[16][128];

    int tid = threadIdx.x;
    int tx = tid & 15, ty = tid >> 4;             // tx 0..15 (col), ty 0..7 (row)
    float acc[16][8] = {};

    for (int k0 = 0; k0 < K; k0 += 16) {
        #pragma unroll
        for (int l = 0; l < 4; ++l) {
            int idx = tid + l * 128;
            int r = idx >> 2, kq = (idx & 3) * 4;
            float4 v = make_float4(0.f, 0.f, 0.f, 0.f);
            int rr = row0 + r;
            if (rr < mval) v = *(const float4*)&A[(size_t)rr * lda + k0 + kq];
            As[kq][r] = v.x; As[kq + 1][r] = v.y; As[kq + 2][r] = v.z; As[kq + 3][r] = v.w;
        }
        #pragma unroll
        for (int l = 0; l < 4; ++l) {
            int idx = tid + l * 128;
            int k = idx >> 5, nq = (idx & 31) * 4;
            *(float4*)&Bs[k][nq] = *(const float4*)&B[(size_t)(k0 + k) * ldb + col0 + nq];
        }
        __syncthreads();
        #pragma unroll
        for (int kk = 0; kk < 16; ++kk) {
            float a0[16], b0[8];
            *(float4*)&a0[0]  = *(const float4*)&As[kk][ty * 16];
            *(float4*)&a0[4]  = *(const float4*)&As[kk][ty * 16 + 4];
            *(float4*)&a0[8]  = *(const float4*)&As[kk][ty * 16 + 8];
            *(float4*)&a0[12] = *(const float4*)&As[kk][ty * 16 + 12];
            *(float4*)&b0[0] = *(const float4*)&Bs[kk][tx * 4];          // 2-way banks: free
            *(float4*)&b0[4] = *(const float4*)&Bs[kk][64 + tx * 4];
            #pragma unroll
            for (int i = 0; i < 16; ++i)
                #pragma unroll
                for (int jn = 0; jn < 8; ++jn)
                    acc[i][jn] = fmaf(a0[i], b0[jn], acc[i][jn]);
        }
        __syncthreads();
    }

    #pragma unroll
    for (int i = 0; i < 16; ++i) {
        int r = row0 + ty * 16 + i;
        if (r >= mval) continue;
        float o0[4], o1[4];
        #pragma unroll
        for (int jn = 0; jn < 4; ++jn) {
            o0[jn] = acc[i][jn]     + (bias ? bias[col0 + tx * 4 + jn]      : 0.0f);
            o1[jn] = acc[i][jn + 4] + (bias ? bias[col0 + 64 + tx * 4 + jn] : 0.0f);
        }
        *(float4*)&C[(size_t)r * ldc + col0 + tx * 4]      = *(float4*)&o0[0];
        *(float4*)&C[(size_t)r * ldc + col0 + 64 + tx * 4] = *(float4*)&o1[0];
    }
}

__global__ __launch_bounds__(128, 2) void k_tgemm(
    size_t Aoff, int lda, size_t Boff, int ldb, size_t biasOff,
    size_t Coff, int ldc, int M, size_t mdevOff, int K)
{
    int mval = (mdevOff == NOFF) ? M : *(const int*)(g_pool + mdevOff);
    int row0 = blockIdx.x * 128, col0 = blockIdx.y * 128;
    if (row0 >= mval) return;
    gemm128_body(g_pool + Aoff, lda, g_pool + Boff, ldb,
                 (biasOff == NOFF) ? nullptr : g_pool + biasOff,
                 g_pool + Coff, ldc, mval, row0, col0, K);
}

// z-batched DH projections (64-tile: more blocks, shorter critical path)
__global__ __launch_bounds__(256) void k_zgemm(
    const float* __restrict__ wk, const float* __restrict__ wv)
{
    int z = blockIdx.z;
    int mval = *(const int*)(g_pool + ((z < 2) ? (oB1 + 4) : (oB2 + 4)));
    int row0 = blockIdx.x * 64, col0 = blockIdx.y * 64;
    if (row0 >= mval) return;
    const float* A = g_pool + ((z < 2) ? oDAT1 : oDAT2) + (size_t)(z & 1) * E;
    const float* B = (z & 1) ? wv : wk;
    float* C = g_pool + oDH1K + (size_t)z * N0 * E;
    gemm64_body(A, F, B, E, nullptr, C, E, mval, row0, col0, E, E);
}

// ---------------- fused shift-sum(u) + eu ----------------
__global__ void k_huev(
    size_t boundsOff, size_t bufYOff,
    const float* __restrict__ b1, const float* __restrict__ w2, const float* __restrict__ b2,
    size_t euOff, size_t mdevOff, int M)
{
    int i = blockIdx.x;
    int mval = (mdevOff == NOFF) ? M : *(const int*)(g_pool + mdevOff);
    if (i >= mval) return;
    int n = threadIdx.x;

    __shared__ float t[HID];
    const int* bounds = (const int*)(g_pool + boundsOff);
    int b1i = bounds[1], b2i = bounds[2], b3i = bounds[3];
    int s = (i >= b1i) + (i >= b2i) + (i >= b3i);
    int st = (s == 0) ? 0 : ((s == 1) ? b1i : ((s == 2) ? b2i : b3i));
    int qp = i - st;

    const float* Y = g_pool + oYB;
    const float* bufY = g_pool + bufYOff;

    if (n < HID) {
        float acc = b1[n];
        #pragma unroll
        for (int j = 0; j < WSZ; ++j) {
            int sp = qp - j;
            const float* row = (sp >= 0) ? &Y[(size_t)(i - j) * NY]
                                         : &bufY[(size_t)(15 + sp) * NY];
            acc += row[j * HID + n];
        }
        t[n] = geluf(acc) * w2[n];
    }
    __syncthreads();
    if (n == 0) {
        float v = b2[0];
        for (int k = 0; k < HID; ++k) v += t[k];
        v = (v > 0.0f) ? v : expm1f(v);
        g_pool[euOff + i] = v + 1.0f;
    }
}

// ---------------- selection scan: serial f32 prefix (bit-exact) + parallel rest ----------------
__global__ __launch_bounds__(256) void k_select(
    size_t euOff, size_t boundsOff, int win,
    size_t selOff, size_t tmOff, size_t euSelOff, size_t boundsNextOff)
{
    __shared__ __align__(16) float se[N0];
    __shared__ __align__(16) float run[N0];
    __shared__ int sFlag[N0];
    __shared__ int sSum[256];
    __shared__ float sCz[NBAT];
    __shared__ int sEc[NBAT];
    __shared__ int sB[5];

    int tid = threadIdx.x;
    const int* bounds = (const int*)(g_pool + boundsOff);
    if (tid < 5) sB[tid] = bounds[tid];
    __syncthreads();
    int N = sB[4];
    for (int i = tid; i < N; i += 256) se[i] = g_pool[euOff + i];
    __syncthreads();

    if (tid == 0) {
        float r = 0.0f;
        int g = 0;
        for (; g + 8 <= N; g += 8) {
            float4 a = *(const float4*)&se[g];
            float4 b4 = *(const float4*)&se[g + 4];
            r += a.x;  run[g]     = r;
            r += a.y;  run[g + 1] = r;
            r += a.z;  run[g + 2] = r;
            r += a.w;  run[g + 3] = r;
            r += b4.x; run[g + 4] = r;
            r += b4.y; run[g + 5] = r;
            r += b4.z; run[g + 6] = r;
            r += b4.w; run[g + 7] = r;
        }
        for (; g < N; ++g) { r += se[g]; run[g] = r; }
        float e0 = run[sB[1] - 1], e1 = run[sB[2] - 1], e2 = run[sB[3] - 1];
        float su0 = e0;
        float su1 = e2 - e1;
        float su2 = run[sB[4] - 1] - e2;
        sCz[0] = 0.0f;
        sCz[1] = su0;
        sCz[2] = su0 + su1;
        sCz[3] = (su0 + su1) + su2;
    }
    __syncthreads();

    for (int g = tid; g < N; g += 256) {
        int seg = (g >= sB[1]) + (g >= sB[2]) + (g >= sB[3]);
        int st = (seg == 0) ? 0 : sB[seg];
        int qp1 = g - st + 1;
        float r2 = run[g] - sCz[seg];
        bool seld = (se[g] > r2 / (float)qp1) || (qp1 <= win);
        sFlag[g] = seld ? 1 : 0;
    }
    __syncthreads();

    int CH = (N + 255) >> 8;
    int lo = tid * CH, hi = min(lo + CH, N);
    {
        int s = 0;
        for (int g = lo; g < hi; ++g) s += sFlag[g];
        sSum[tid] = s;
    }
    __syncthreads();
    if (tid == 0) {
        int acc = 0;
        for (int t = 0; t < 256; ++t) { int v = sSum[t]; sSum[t] = acc; acc += v; }
    }
    __syncthreads();

    int* sel = (int*)(g_pool + selOff);
    int* tm  = (int*)(g_pool + tmOff);
    float* eus = g_pool + euSelOff;
    int* bn  = (int*)(g_pool + boundsNextOff);

    int csel0 = sFlag[0];
    {
        int csel = sSum[tid];
        for (int g = lo; g < hi; ++g) {
            csel += sFlag[g];
            tm[g] = csel - csel0;
            if (sFlag[g]) { sel[csel - 1] = g; eus[csel - 1] = se[g]; }
            #pragma unroll
            for (int s = 0; s < NBAT; ++s)
                if (g == sB[s + 1] - 1) sEc[s] = csel;
        }
    }
    __syncthreads();
    if (tid == 0) {
        bn[0] = 0; bn[1] = sEc[0]; bn[2] = sEc[1]; bn[3] = sEc[2]; bn[4] = sEc[3];
    }
}

// ---------------- fused shift-sum(d) + r-softmax + dat ----------------
__global__ __launch_bounds__(256) void k_rdat(
    size_t boundsOff, size_t bufYOff,
    const float* __restrict__ b1, const float* __restrict__ w2, const float* __restrict__ b2,
    size_t selOff, size_t mdevOff,
    size_t srcOff, int srcStr, const float* __restrict__ buf,
    size_t datOff)
{
    int i = blockIdx.x;
    if (i >= *(const int*)(g_pool + mdevOff)) return;
    const float* src = g_pool + srcOff;
    const int* bounds = (const int*)(g_pool + boundsOff);
    const int* sel = (const int*)(g_pool + selOff);
    float* dat = g_pool + datOff;

    __shared__ float gh[HID];
    __shared__ float sv[WSZ];
    __shared__ float r[WSZ];
    __shared__ int sG, sQp;

    int tid = threadIdx.x;
    if (tid == 0) {
        int g = sel[i];
        int b1i = bounds[1], b2i = bounds[2], b3i = bounds[3];
        int s = (g >= b1i) + (g >= b2i) + (g >= b3i);
        int st = (s == 0) ? 0 : ((s == 1) ? b1i : ((s == 2) ? b2i : b3i));
        sG = g; sQp = g - st;
    }
    __syncthreads();
    int g = sG, qp = sQp;

    if (tid < HID) {
        const float* Y = g_pool + oYB;
        const float* bufY = g_pool + bufYOff;
        float acc = b1[tid];
        #pragma unroll
        for (int j = 0; j < WSZ; ++j) {
            int sp = qp - j;
            const float* row = (sp >= 0) ? &Y[(size_t)(g - j) * NY]
                                         : &bufY[(size_t)(15 + sp) * NY];
            acc += row[NY / 2 + j * HID + tid];
        }
        gh[tid] = geluf(acc);
    }
    __syncthreads();
    if (tid < WSZ) {
        float acc = 0.0f;
        for (int k = 0; k < HID; ++k) acc += gh[k] * w2[k * WSZ + tid];
        sv[tid] = acc + b2[tid];
    }
    __syncthreads();
    if (tid == 0) {
        float m = sv[0];
        for (int t = 1; t < WSZ; ++t) m = fmaxf(m, sv[t]);
        float sum = 0.0f;
        for (int t = 0; t < WSZ; ++t) { float e = expf(sv[t] - m); r[t] = e; sum += e; }
        for (int t = 0; t < WSZ; ++t) r[t] = r[t] / sum;
    }
    __syncthreads();
    for (int f = tid; f < F; f += 256) {
        float acc = 0.0f;
        for (int j = 0; j < WSZ; ++j) {
            int sp = qp - j;
            float v = (sp >= 0) ? src[(size_t)(g - j) * srcStr + f]
                                : buf[(size_t)(15 + sp) * F + f];
            acc = fmaf(r[j], v, acc);
        }
        dat[(size_t)i * F + f] = acc;
    }
}

// ---------------- fused attention over 48 gathered kv slots ----------------
__global__ __launch_bounds__(512) void k_attn(
    const float* __restrict__ bk, const float* __restrict__ bv)
{
    int g = blockIdx.x;
    const float* XO   = g_pool + oXO;
    const float* BH0k = g_pool + oBH0K;
    const float* BH0v = g_pool + oBH0V;
    const float* DH1k = g_pool + oDH1K;
    const float* DH1v = g_pool + oDH1V;
    const float* DH2k = g_pool + oDH2K;
    const float* DH2v = g_pool + oDH2V;
    const float* eus0 = g_pool + oEUS0;
    const float* eus1 = g_pool + oEUS1;
    const int* tm0 = (const int*)(g_pool + oTM0);
    const int* tm1 = (const int*)(g_pool + oTM1);
    const int* bounds1 = (const int*)(g_pool + oB1);
    const int* bounds2 = (const int*)(g_pool + oB2);

    __shared__ const float* sK[48];
    __shared__ const float* sV[48];
    __shared__ float sScale[48];
    __shared__ __align__(16) float sQ[E], sBk[E], sBv[E];
    __shared__ float sc[48][8];

    int tid = threadIdx.x;
    sQ[tid]  = XO[(size_t)g * XSTR + 2048 + tid];
    sBk[tid] = bk[tid];
    sBv[tid] = bv[tid];

    if (tid < 48) {
        int s = tid;
        const float *pK = nullptr, *pV = nullptr;
        float scl = 0.0f;
        if (s < 16) {
            int s0 = (g >= 768) + (g >= 1408) + (g >= 2112);
            const int st0[4] = {0, 768, 1408, 2112};
            int sp = (g - st0[s0]) - s;
            if (sp >= 0) { pK = XO + (size_t)(g - s) * XSTR + 1024; pV = XO + (size_t)(g - s) * XSTR + 1536; }
            else         { pK = BH0k + (size_t)(15 + sp) * E; pV = BH0v + (size_t)(15 + sp) * E; }
            scl = 1.0f;
        } else if (s < 32) {
            int j = s - 16;
            int i1 = tm0[g];
            int b1 = bounds1[1], b2 = bounds1[2], b3 = bounds1[3];
            int sg = (i1 >= b1) + (i1 >= b2) + (i1 >= b3);
            int st = (sg == 0) ? 0 : ((sg == 1) ? b1 : ((sg == 2) ? b2 : b3));
            int sp = (i1 - st) - j;
            if (sp >= 0) { pK = DH1k + (size_t)(i1 - j) * E; pV = DH1v + (size_t)(i1 - j) * E; scl = eus0[i1 - j]; }
        } else {
            int j = s - 32;
            int i1 = tm0[g];
            int i2 = tm1[i1];
            int b1 = bounds2[1], b2 = bounds2[2], b3 = bounds2[3];
            int sg = (i2 >= b1) + (i2 >= b2) + (i2 >= b3);
            int st = (sg == 0) ? 0 : ((sg == 1) ? b1 : ((sg == 2) ? b2 : b3));
            int sp = (i2 - st) - j;
            if (sp >= 0) { pK = DH2k + (size_t)(i2 - j) * E; pV = DH2v + (size_t)(i2 - j) * E; scl = eus1[i2 - j]; }
        }
        sK[s] = pK; sV[s] = pV; sScale[s] = scl;
    }
    __syncthreads();

    if (tid < 384) {
        int s = tid >> 3, h = tid & 7;
        const float* bp = sK[s];
        float scl = sScale[s];
        float acc = 0.0f;
        int d0 = h * 64;
        if (s < 16) {
            for (int d = 0; d < 64; d += 4) {
                float4 qv = *(const float4*)&sQ[d0 + d];
                float4 kv4 = *(const float4*)&bp[d0 + d];
                acc += qv.x * kv4.x; acc += qv.y * kv4.y;
                acc += qv.z * kv4.z; acc += qv.w * kv4.w;
            }
        } else if (bp) {
            for (int d = 0; d < 64; d += 4) {
                float4 qv = *(const float4*)&sQ[d0 + d];
                float4 kv4 = *(const float4*)&bp[d0 + d];
                float4 bb = *(const float4*)&sBk[d0 + d];
                acc += qv.x * (bb.x + scl * kv4.x); acc += qv.y * (bb.y + scl * kv4.y);
                acc += qv.z * (bb.z + scl * kv4.z); acc += qv.w * (bb.w + scl * kv4.w);
            }
        } else {
            for (int d = 0; d < 64; d += 4) {
                float4 qv = *(const float4*)&sQ[d0 + d];
                float4 bb = *(const float4*)&sBk[d0 + d];
                acc += qv.x * bb.x; acc += qv.y * bb.y;
                acc += qv.z * bb.z; acc += qv.w * bb.w;
            }
        }
        sc[s][h] = acc * 0.125f;   // / sqrt(64)
    }
    __syncthreads();

    if (tid < 8) {
        int h = tid;
        float m = sc[0][h];
        for (int s = 1; s < 48; ++s) m = fmaxf(m, sc[s][h]);
        float sum = 0.0f;
        for (int s = 0; s < 48; ++s) { float e = expf(sc[s][h] - m); sc[s][h] = e; sum += e; }
        for (int s = 0; s < 48; ++s) sc[s][h] = sc[s][h] / sum;
    }
    __syncthreads();

    {
        int d = tid, h = d >> 6;
        float acc = 0.0f;
        for (int s = 0; s < 48; ++s) {
            const float* bp = sV[s];
            float vv;
            if (s < 16) vv = bp[d];
            else        vv = sBv[d] + (bp ? sScale[s] * bp[d] : 0.0f);
            acc = fmaf(sc[s][h], vv, acc);
        }
        g_pool[oCTX + (size_t)g * E + d] = acc;
    }
}

// ---------------- y2 -> out (B, 768, E) with zero padding ----------------
__global__ __launch_bounds__(256) void k_scatter(float* __restrict__ out) {
    int idx = blockIdx.x * 256 + threadIdx.x;
    if (idx >= NBAT * MAXL * E) return;
    int d = idx & (E - 1);
    int rest = idx >> 9;
    int p = rest % MAXL, bb = rest / MAXL;
    const int st[4] = {0, 768, 1408, 2112};
    const int ln[4] = {768, 640, 704, 600};
    out[idx] = (p < ln[bb]) ? g_pool[oY2 + (size_t)(st[bb] + p) * E + d] : 0.0f;
}

// ================================================================================
extern "C" void kernel_launch(void* const* d_in, const int* in_sizes, int n_in,
                              void* d_out, int out_size, void* d_ws, size_t ws_size,
                              hipStream_t stream)
{
    (void)in_sizes; (void)n_in; (void)d_ws; (void)ws_size; (void)out_size;

    const float* x      = (const float*)d_in[0];
    const float* kv_w   = (const float*)d_in[2];
    const float* kv_b   = (const float*)d_in[3];
    const float* q_w    = (const float*)d_in[4];
    const float* q_b    = (const float*)d_in[5];
    const float* proj_w = (const float*)d_in[6];
    const float* proj_b = (const float*)d_in[7];
    const float* buf0   = (const float*)d_in[8];
    const float* buf1   = (const float*)d_in[9];
    const float* d0_w1  = (const float*)d_in[11];
    const float* d0_b1  = (const float*)d_in[12];
    const float* d0_w2  = (const float*)d_in[13];
    const float* d0_b2  = (const float*)d_in[14];
    const float* u0_w1  = (const float*)d_in[15];
    const float* u0_b1  = (const float*)d_in[16];
    const float* u0_w2  = (const float*)d_in[17];
    const float* u0_b2  = (const float*)d_in[18];
    const float* d1_w1  = (const float*)d_in[19];
    const float* d1_b1  = (const float*)d_in[20];
    const float* d1_w2  = (const float*)d_in[21];
    const float* d1_b2  = (const float*)d_in[22];
    const float* u1_w1  = (const float*)d_in[23];
    const float* u1_b1  = (const float*)d_in[24];
    const float* u1_w2  = (const float*)d_in[25];
    const float* u1_b2  = (const float*)d_in[26];
    const float* wq     = (const float*)d_in[27];
    const float* bq     = (const float*)d_in[28];
    const float* wk     = (const float*)d_in[29];
    const float* bk     = (const float*)d_in[30];
    const float* wv     = (const float*)d_in[31];
    const float* bv     = (const float*)d_in[32];
    const float* out_w  = (const float*)d_in[33];
    const float* out_b  = (const float*)d_in[34];

    auto cdiv = [](int a, int b) { return (a + b - 1) / b; };
    auto GT = [&](int M, int N) { return dim3(cdiv(M, 128), cdiv(N, 128)); };

    k_init<<<1, 64, 0, stream>>>();
    k_xflat<<<cdiv(N0 * E, 256), 256, 0, stream>>>(x);

    // ---- weight prep ----
    k_reshape<<<cdiv(F * NY, 256), 256, 0, stream>>>(u0_w1, d0_w1, oBD0);
    k_reshape<<<cdiv(F * NY, 256), 256, 0, stream>>>(u1_w1, d1_w1, oBD1);
    k_copymat<<<cdiv(E * F, 256), 256, 0, stream>>>(kv_w, oWX, E, F, F, XSTR);
    k_wprep<<<dim3(8, 8, 4), 256, 0, stream>>>(kv_w, q_w, out_w, wk, wv, wq, proj_w);
    k_prepvec<<<cdiv(3072, 256), 256, 0, stream>>>(kv_b, q_b, out_b, wk, bk, wv, bv, wq, bq, proj_w, proj_b);
    k_bufy<<<dim3(1, NY / 64, 2), 256, 0, stream>>>(buf0, buf1);
    k_bh<<<dim3(1, E / 64, 2), 256, 0, stream>>>(buf0, wk, bk, wv, bv);

    // ---- X-GEMM: XO = xf @ WX + XB  -> [kv0 | KH0 | VH0 | qh] ----
    k_tgemm<<<GT(N0, XSTR), 128, 0, stream>>>(oXF, E, oWX, XSTR, oXB, oXO, XSTR, N0, NOFF, E);

    // ---- level 0 ----
    k_tgemm<<<GT(N0, NY), 128, 0, stream>>>(oXO, XSTR, oBD0, NY, NOFF, oYB, NY, N0, NOFF, F);
    k_huev<<<N0, 160, 0, stream>>>(oB0, oBUFY0, u0_b1, u0_w2, u0_b2, oEU0, NOFF, N0);
    k_select<<<1, 256, 0, stream>>>(oEU0, oB0, WSZ, oSEL0, oTM0, oEUS0, oB1);
    k_rdat<<<N0, 256, 0, stream>>>(oB0, oBUFY0, d0_b1, d0_w2, d0_b2, oSEL0, oB1 + 4, oXO, XSTR, buf0, oDAT1);

    // ---- level 1 ----
    k_tgemm<<<GT(N0, NY), 128, 0, stream>>>(oDAT1, F, oBD1, NY, NOFF, oYB, NY, N0, oB1 + 4, F);
    k_huev<<<N0, 160, 0, stream>>>(oB1, oBUFY1, u1_b1, u1_w2, u1_b2, oEU1, oB1 + 4, N0);
    k_select<<<1, 256, 0, stream>>>(oEU1, oB1, WSZ, oSEL1, oTM1, oEUS1, oB2);
    k_rdat<<<N0, 256, 0, stream>>>(oB1, oBUFY1, d1_b1, d1_w2, d1_b2, oSEL1, oB2 + 4, oDAT1, F, buf1, oDAT2);

    // ---- DH projections (z-batched, 64-tile) ----
    k_zgemm<<<dim3(cdiv(N0, 64), E / 64, 4), 256, 0, stream>>>(wk, wv);

    // ---- fused attention + combined output projection + scatter ----
    k_attn<<<N0, 512, 0, stream>>>(bk, bv);
    k_pgemm<<<dim3(cdiv(N0, 64), E / 64), 256, 0, stream>>>(oCTX, E, oWOP, E, oBOP, oY2, E, N0, NOFF, E, E);
    k_scatter<<<cdiv(NBAT * MAXL * E, 256), 256, 0, stream>>>((float*)d_out);
}

// Round 7
// 1379.663 us; speedup vs baseline: 1.7212x; 1.1320x over previous
//
#include <hip/hip_runtime.h>
#include <cstddef>

#define DEVFN __device__ __forceinline__

constexpr int N0   = 2712;             // 768+640+704+600
constexpr int MAXL = 768;
constexpr int NBAT = 4;
constexpr int E    = 512;
constexpr int F    = 1024;
constexpr int HID  = 160;
constexpr int WSZ  = 16;               // window length
constexpr int NY   = 2 * WSZ * HID;    // 5120: [u | d] fused Y width
constexpr int XSTR = 2560;             // XO row: [kv0(1024) | KH0(512) | VH0(512) | qh(512)]
constexpr size_t NOFF = (size_t)-1;

// ---------------- static device scratch pool (offsets in floats) ----------------
constexpr size_t oXF    = 0;
constexpr size_t oXO    = oXF    + (size_t)N0*E;
constexpr size_t oEU0   = oXO    + (size_t)N0*XSTR;
constexpr size_t oDAT1  = oEU0   + (size_t)N0;
constexpr size_t oEU1   = oDAT1  + (size_t)N0*F;
constexpr size_t oDAT2  = oEU1   + (size_t)N0;
constexpr size_t oBH0K  = oDAT2  + (size_t)N0*F;
constexpr size_t oBH0V  = oBH0K  + (size_t)15*E;
constexpr size_t oDH1K  = oBH0V  + (size_t)15*E;   // DH1K,DH1V,DH2K,DH2V contiguous
constexpr size_t oDH1V  = oDH1K  + (size_t)N0*E;
constexpr size_t oDH2K  = oDH1V  + (size_t)N0*E;
constexpr size_t oDH2V  = oDH2K  + (size_t)N0*E;
constexpr size_t oCTX   = oDH2V  + (size_t)N0*E;
constexpr size_t oY2    = oCTX   + (size_t)N0*E;
constexpr size_t oEUS0  = oY2    + (size_t)N0*E;
constexpr size_t oEUS1  = oEUS0  + (size_t)N0;
constexpr size_t oSEL0  = oEUS1  + (size_t)N0;
constexpr size_t oTM0   = oSEL0  + (size_t)N0;
constexpr size_t oSEL1  = oTM0   + (size_t)N0;
constexpr size_t oTM1   = oSEL1  + (size_t)N0;
constexpr size_t oB0    = oTM1   + (size_t)N0;
constexpr size_t oB1    = oB0    + 8;
constexpr size_t oB2    = oB1    + 8;
constexpr size_t oWOP   = oB2    + 8;
constexpr size_t oBOP   = oWOP   + (size_t)E*E;
constexpr size_t oWX    = oBOP   + E;              // 512 x 2560
constexpr size_t oXB    = oWX    + (size_t)E*XSTR; // 2560 bias
constexpr size_t oBD0   = oXB    + XSTR;
constexpr size_t oBD1   = oBD0   + (size_t)F*NY;
constexpr size_t oBUFY0 = oBD1   + (size_t)F*NY;
constexpr size_t oBUFY1 = oBUFY0 + (size_t)15*NY;
constexpr size_t oYB    = oBUFY1 + (size_t)15*NY;
constexpr size_t oEND   = oYB    + (size_t)N0*NY;

__device__ float g_pool[oEND];

DEVFN float geluf(float x) {
    return 0.5f * x * (1.0f + erff(x / 1.41421356237309504880f));
}

// ---------------- tiny init ----------------
__global__ void k_init() {
    if (threadIdx.x == 0) {
        int* b = (int*)(g_pool + oB0);
        b[0] = 0; b[1] = 768; b[2] = 1408; b[3] = 2112; b[4] = N0;
    }
}

// ---------------- x (B,768,E) -> x_flat (N0,E) ----------------
__global__ __launch_bounds__(256) void k_xflat(const float* __restrict__ x) {
    int idx = blockIdx.x * 256 + threadIdx.x;
    if (idx >= N0 * E) return;
    int d = idx & (E - 1);
    int g = idx >> 9;
    int s = (g >= 768) + (g >= 1408) + (g >= 2112);
    const int st[4] = {0, 768, 1408, 2112};
    int qp = g - st[s];
    g_pool[oXF + idx] = x[((size_t)s * MAXL + qp) * E + d];
}

// ---------------- w1 (16384,160) pairs -> BD (1024, 5120) ----------------
__global__ __launch_bounds__(256) void k_reshape(
    const float* __restrict__ uw, const float* __restrict__ dw, size_t bdOff)
{
    int idx = blockIdx.x * 256 + threadIdx.x;
    if (idx >= F * NY) return;
    int col = idx % NY;
    int f = idx / NY;
    const float* src = (col < NY / 2) ? uw : dw;
    int rem = (col < NY / 2) ? col : col - NY / 2;
    int j = rem / HID, n = rem % HID;
    g_pool[bdOff + idx] = src[((size_t)j * F + f) * HID + n];
}

// ---------------- kv_w -> WX[:, 0:1024] ----------------
__global__ __launch_bounds__(256) void k_copymat(
    const float* __restrict__ src, size_t dstOff, int rows, int cols, int lds, int ldd)
{
    int idx = blockIdx.x * 256 + threadIdx.x;
    if (idx >= rows * cols) return;
    int r = idx / cols, c = idx % cols;
    g_pool[dstOff + (size_t)r * ldd + c] = src[(size_t)r * lds + c];
}

// ---------------- fused bias prep: XB[2560] + BOP[512] ----------------
__global__ __launch_bounds__(256) void k_prepvec(
    const float* __restrict__ kv_b, const float* __restrict__ q_b, const float* __restrict__ out_b,
    const float* __restrict__ wk, const float* __restrict__ bk,
    const float* __restrict__ wv, const float* __restrict__ bv,
    const float* __restrict__ wq, const float* __restrict__ bq,
    const float* __restrict__ proj_w, const float* __restrict__ proj_b)
{
    int idx = blockIdx.x * 256 + threadIdx.x;
    if (idx >= 3072) return;
    if (idx < 1024) { g_pool[oXB + idx] = kv_b[idx]; return; }
    const float* vec; const float* W; const float* add; int n; size_t dst;
    if (idx < 1536)      { n = idx - 1024; vec = kv_b;     W = wk;     add = bk;     dst = oXB + idx; }
    else if (idx < 2048) { n = idx - 1536; vec = kv_b + E; W = wv;     add = bv;     dst = oXB + idx; }
    else if (idx < 2560) { n = idx - 2048; vec = q_b;      W = wq;     add = bq;     dst = oXB + idx; }
    else                 { n = idx - 2560; vec = out_b;    W = proj_w; add = proj_b; dst = oBOP + n; }
    float s = add[n];
    for (int k = 0; k < E; ++k) s = fmaf(vec[k], W[(size_t)k * E + n], s);
    g_pool[dst] = s;
}

// ---------------- 64x64 f32 GEMM body (4x4 micro, 256 threads) ----------------
DEVFN void gemm64_body(
    const float* __restrict__ A, int lda,
    const float* __restrict__ B, int ldb,
    const float* __restrict__ bias,
    float* __restrict__ C, int ldc,
    int mval, int row0, int col0, int K, int N)
{
    __shared__ __align__(16) float As[32][68];
    __shared__ __align__(16) float Bs[32][64];

    int tid = threadIdx.x;
    float acc[4][4] = {};
    int tx = tid & 15, ty = tid >> 4;

    for (int k0 = 0; k0 < K; k0 += 32) {
        #pragma unroll
        for (int l = 0; l < 8; ++l) {
            int idx = tid + l * 256;
            int kk = idx & 31, m = idx >> 5;
            int r = row0 + m;
            float v = 0.0f;
            if (r < mval) v = A[(size_t)r * lda + k0 + kk];
            As[kk][m] = v;
        }
        #pragma unroll
        for (int l = 0; l < 8; ++l) {
            int idx = tid + l * 256;
            int n = idx & 63, kk = idx >> 6;
            int col = col0 + n;
            float v = 0.0f;
            if (col < N) v = B[(size_t)(k0 + kk) * ldb + col];
            Bs[kk][n] = v;
        }
        __syncthreads();
        #pragma unroll
        for (int kk = 0; kk < 32; ++kk) {
            float4 a4 = *(const float4*)&As[kk][ty * 4];
            float4 b4 = *(const float4*)&Bs[kk][tx * 4];
            float av[4] = {a4.x, a4.y, a4.z, a4.w};
            float bv[4] = {b4.x, b4.y, b4.z, b4.w};
            #pragma unroll
            for (int i = 0; i < 4; ++i)
                #pragma unroll
                for (int jn = 0; jn < 4; ++jn)
                    acc[i][jn] = fmaf(av[i], bv[jn], acc[i][jn]);
        }
        __syncthreads();
    }

    #pragma unroll
    for (int i = 0; i < 4; ++i) {
        int r = row0 + ty * 4 + i;
        if (r >= mval) continue;
        #pragma unroll
        for (int jn = 0; jn < 4; ++jn) {
            int col = col0 + tx * 4 + jn;
            if (col < N)
                C[(size_t)r * ldc + col] = acc[i][jn] + (bias ? bias[col] : 0.0f);
        }
    }
}

// generic pool-based 64-tile GEMM (y2 projection)
__global__ __launch_bounds__(256) void k_pgemm(
    size_t Aoff, int lda, size_t Boff, int ldb, size_t biasOff,
    size_t Coff, int ldc, int M, size_t mdevOff, int K, int N)
{
    int mval = (mdevOff == NOFF) ? M : *(const int*)(g_pool + mdevOff);
    int row0 = blockIdx.x * 64, col0 = blockIdx.y * 64;
    if (row0 >= mval) return;
    gemm64_body(g_pool + Aoff, lda, g_pool + Boff, ldb,
                (biasOff == NOFF) ? nullptr : g_pool + biasOff,
                g_pool + Coff, ldc, mval, row0, col0, K, N);
}

// z-batched weight-prep: {kv_w_k@wk, kv_w_v@wv, q_w@wq, out_w@proj_w}
__global__ __launch_bounds__(256) void k_wprep(
    const float* __restrict__ kv_w, const float* __restrict__ q_w, const float* __restrict__ out_w,
    const float* __restrict__ wk, const float* __restrict__ wv,
    const float* __restrict__ wq, const float* __restrict__ proj_w)
{
    int z = blockIdx.z;
    const float* A; int lda; const float* B; float* C; int ldc;
    if (z == 0)      { A = kv_w;     lda = F; B = wk;     C = g_pool + oWX + 1024; ldc = XSTR; }
    else if (z == 1) { A = kv_w + E; lda = F; B = wv;     C = g_pool + oWX + 1536; ldc = XSTR; }
    else if (z == 2) { A = q_w;      lda = E; B = wq;     C = g_pool + oWX + 2048; ldc = XSTR; }
    else             { A = out_w;    lda = E; B = proj_w; C = g_pool + oWOP;       ldc = E;    }
    gemm64_body(A, lda, B, E, nullptr, C, ldc, E, blockIdx.x * 64, blockIdx.y * 64, E, E);
}

// z-batched bufY: {buf0@BD0, buf1@BD1}
__global__ __launch_bounds__(256) void k_bufy(
    const float* __restrict__ buf0, const float* __restrict__ buf1)
{
    int z = blockIdx.z;
    const float* A = z ? buf1 : buf0;
    const float* B = g_pool + (z ? oBD1 : oBD0);
    float* C = g_pool + (z ? oBUFY1 : oBUFY0);
    gemm64_body(A, F, B, NY, nullptr, C, NY, 15, 0, blockIdx.y * 64, F, NY);
}

// z-batched buffer K/V projections: {buf0_k@wk+bk, buf0_v@wv+bv}
__global__ __launch_bounds__(256) void k_bh(
    const float* __restrict__ buf0,
    const float* __restrict__ wk, const float* __restrict__ bk,
    const float* __restrict__ wv, const float* __restrict__ bv)
{
    int z = blockIdx.z;
    const float* A = buf0 + (size_t)z * E;
    const float* B = z ? wv : wk;
    const float* bias = z ? bv : bk;
    float* C = g_pool + (z ? oBH0V : oBH0K);
    gemm64_body(A, F, B, E, bias, C, E, 15, 0, blockIdx.y * 64, E, E);
}

// ---------------- big f32 GEMM: 128x128 tile, 256 threads, 8x8 micro, reg-dbuf ----------------
DEVFN void fma_8x8(const float4& a0, const float4& a1, const float4& b0, const float4& b1,
                   float2 (&acc)[8][4])
{
    float av[8] = {a0.x, a0.y, a0.z, a0.w, a1.x, a1.y, a1.z, a1.w};
    float2 bv[4] = {make_float2(b0.x, b0.y), make_float2(b0.z, b0.w),
                    make_float2(b1.x, b1.y), make_float2(b1.z, b1.w)};
    #pragma unroll
    for (int i = 0; i < 8; ++i) {
        #pragma unroll
        for (int q = 0; q < 4; ++q) {
            acc[i][q].x = fmaf(av[i], bv[q].x, acc[i][q].x);
            acc[i][q].y = fmaf(av[i], bv[q].y, acc[i][q].y);
        }
    }
}

DEVFN void gemm128_body(
    const float* __restrict__ A, int lda,
    const float* __restrict__ B, int ldb,
    const float* __restrict__ bias,
    float* __restrict__ C, int ldc,
    int mval, int row0, int col0, int K)
{
    __shared__ __align__(16) float As[16][132];   // transposed: As[k][m]
    __shared__ __align__(16) float Bs[16][132];

    int tid = threadIdx.x;
    int tx = tid & 15, ty = tid >> 4;             // tx: col quad, ty: row octet
    float2 acc[8][4] = {};

    int ar = tid >> 1, akq = (tid & 1) * 8;       // A staging: row, k-offset
    int bk = tid >> 4, bnq = (tid & 15) * 8;      // B staging: k, n-offset

    for (int k0 = 0; k0 < K; k0 += 16) {
        // stage A (128 rows x 16 k): 2 float4 per thread, transposed store
        {
            float4 v0 = make_float4(0.f, 0.f, 0.f, 0.f), v1 = v0;
            int rr = row0 + ar;
            if (rr < mval) {
                v0 = *(const float4*)&A[(size_t)rr * lda + k0 + akq];
                v1 = *(const float4*)&A[(size_t)rr * lda + k0 + akq + 4];
            }
            As[akq + 0][ar] = v0.x; As[akq + 1][ar] = v0.y;
            As[akq + 2][ar] = v0.z; As[akq + 3][ar] = v0.w;
            As[akq + 4][ar] = v1.x; As[akq + 5][ar] = v1.y;
            As[akq + 6][ar] = v1.z; As[akq + 7][ar] = v1.w;
        }
        // stage B (16 k x 128 n): 2 float4 per thread
        {
            const float* bp = &B[(size_t)(k0 + bk) * ldb + col0 + bnq];
            *(float4*)&Bs[bk][bnq]     = *(const float4*)&bp[0];
            *(float4*)&Bs[bk][bnq + 4] = *(const float4*)&bp[4];
        }
        __syncthreads();

        // register-double-buffered inner loop
        float4 a0A = *(const float4*)&As[0][ty * 8];
        float4 a1A = *(const float4*)&As[0][ty * 8 + 4];
        float4 b0A = *(const float4*)&Bs[0][tx * 4];
        float4 b1A = *(const float4*)&Bs[0][64 + tx * 4];
        #pragma unroll
        for (int kk = 0; kk < 16; kk += 2) {
            float4 a0B = *(const float4*)&As[kk + 1][ty * 8];
            float4 a1B = *(const float4*)&As[kk + 1][ty * 8 + 4];
            float4 b0B = *(const float4*)&Bs[kk + 1][tx * 4];
            float4 b1B = *(const float4*)&Bs[kk + 1][64 + tx * 4];
            fma_8x8(a0A, a1A, b0A, b1A, acc);
            if (kk + 2 < 16) {
                a0A = *(const float4*)&As[kk + 2][ty * 8];
                a1A = *(const float4*)&As[kk + 2][ty * 8 + 4];
                b0A = *(const float4*)&Bs[kk + 2][tx * 4];
                b1A = *(const float4*)&Bs[kk + 2][64 + tx * 4];
            }
            fma_8x8(a0B, a1B, b0B, b1B, acc);
        }
        __syncthreads();
    }

    #pragma unroll
    for (int i = 0; i < 8; ++i) {
        int r = row0 + ty * 8 + i;
        if (r >= mval) continue;
        float o0[4], o1[4];
        o0[0] = acc[i][0].x; o0[1] = acc[i][0].y; o0[2] = acc[i][1].x; o0[3] = acc[i][1].y;
        o1[0] = acc[i][2].x; o1[1] = acc[i][2].y; o1[2] = acc[i][3].x; o1[3] = acc[i][3].y;
        if (bias) {
            #pragma unroll
            for (int jn = 0; jn < 4; ++jn) {
                o0[jn] += bias[col0 + tx * 4 + jn];
                o1[jn] += bias[col0 + 64 + tx * 4 + jn];
            }
        }
        *(float4*)&C[(size_t)r * ldc + col0 + tx * 4]      = *(float4*)&o0[0];
        *(float4*)&C[(size_t)r * ldc + col0 + 64 + tx * 4] = *(float4*)&o1[0];
    }
}

__global__ __launch_bounds__(256) void k_tgemm(
    size_t Aoff, int lda, size_t Boff, int ldb, size_t biasOff,
    size_t Coff, int ldc, int M, size_t mdevOff, int K)
{
    int mval = (mdevOff == NOFF) ? M : *(const int*)(g_pool + mdevOff);
    int row0 = blockIdx.x * 128, col0 = blockIdx.y * 128;
    if (row0 >= mval) return;
    gemm128_body(g_pool + Aoff, lda, g_pool + Boff, ldb,
                 (biasOff == NOFF) ? nullptr : g_pool + biasOff,
                 g_pool + Coff, ldc, mval, row0, col0, K);
}

// z-batched DH projections (64-tile: more blocks, shorter critical path)
__global__ __launch_bounds__(256) void k_zgemm(
    const float* __restrict__ wk, const float* __restrict__ wv)
{
    int z = blockIdx.z;
    int mval = *(const int*)(g_pool + ((z < 2) ? (oB1 + 4) : (oB2 + 4)));
    int row0 = blockIdx.x * 64, col0 = blockIdx.y * 64;
    if (row0 >= mval) return;
    const float* A = g_pool + ((z < 2) ? oDAT1 : oDAT2) + (size_t)(z & 1) * E;
    const float* B = (z & 1) ? wv : wk;
    float* C = g_pool + oDH1K + (size_t)z * N0 * E;
    gemm64_body(A, F, B, E, nullptr, C, E, mval, row0, col0, E, E);
}

// ---------------- fused shift-sum(u) + eu ----------------
__global__ void k_huev(
    size_t boundsOff, size_t bufYOff,
    const float* __restrict__ b1, const float* __restrict__ w2, const float* __restrict__ b2,
    size_t euOff, size_t mdevOff, int M)
{
    int i = blockIdx.x;
    int mval = (mdevOff == NOFF) ? M : *(const int*)(g_pool + mdevOff);
    if (i >= mval) return;
    int n = threadIdx.x;

    __shared__ float t[HID];
    const int* bounds = (const int*)(g_pool + boundsOff);
    int b1i = bounds[1], b2i = bounds[2], b3i = bounds[3];
    int s = (i >= b1i) + (i >= b2i) + (i >= b3i);
    int st = (s == 0) ? 0 : ((s == 1) ? b1i : ((s == 2) ? b2i : b3i));
    int qp = i - st;

    const float* Y = g_pool + oYB;
    const float* bufY = g_pool + bufYOff;

    if (n < HID) {
        float acc = b1[n];
        #pragma unroll
        for (int j = 0; j < WSZ; ++j) {
            int sp = qp - j;
            const float* row = (sp >= 0) ? &Y[(size_t)(i - j) * NY]
                                         : &bufY[(size_t)(15 + sp) * NY];
            acc += row[j * HID + n];
        }
        t[n] = geluf(acc) * w2[n];
    }
    __syncthreads();
    if (n == 0) {
        float v = b2[0];
        for (int k = 0; k < HID; ++k) v += t[k];
        v = (v > 0.0f) ? v : expm1f(v);
        g_pool[euOff + i] = v + 1.0f;
    }
}

// ---------------- selection scan: serial f32 prefix (bit-exact) + parallel rest ----------------
__global__ __launch_bounds__(256) void k_select(
    size_t euOff, size_t boundsOff, int win,
    size_t selOff, size_t tmOff, size_t euSelOff, size_t boundsNextOff)
{
    __shared__ __align__(16) float se[N0];
    __shared__ __align__(16) float run[N0];
    __shared__ int sFlag[N0];
    __shared__ int sSum[256];
    __shared__ float sCz[NBAT];
    __shared__ int sEc[NBAT];
    __shared__ int sB[5];

    int tid = threadIdx.x;
    const int* bounds = (const int*)(g_pool + boundsOff);
    if (tid < 5) sB[tid] = bounds[tid];
    __syncthreads();
    int N = sB[4];
    for (int i = tid; i < N; i += 256) se[i] = g_pool[euOff + i];
    __syncthreads();

    if (tid == 0) {
        float r = 0.0f;
        int g = 0;
        for (; g + 8 <= N; g += 8) {
            float4 a = *(const float4*)&se[g];
            float4 b4 = *(const float4*)&se[g + 4];
            r += a.x;  run[g]     = r;
            r += a.y;  run[g + 1] = r;
            r += a.z;  run[g + 2] = r;
            r += a.w;  run[g + 3] = r;
            r += b4.x; run[g + 4] = r;
            r += b4.y; run[g + 5] = r;
            r += b4.z; run[g + 6] = r;
            r += b4.w; run[g + 7] = r;
        }
        for (; g < N; ++g) { r += se[g]; run[g] = r; }
        float e0 = run[sB[1] - 1], e1 = run[sB[2] - 1], e2 = run[sB[3] - 1];
        float su0 = e0;
        float su1 = e2 - e1;
        float su2 = run[sB[4] - 1] - e2;
        sCz[0] = 0.0f;
        sCz[1] = su0;
        sCz[2] = su0 + su1;
        sCz[3] = (su0 + su1) + su2;
    }
    __syncthreads();

    for (int g = tid; g < N; g += 256) {
        int seg = (g >= sB[1]) + (g >= sB[2]) + (g >= sB[3]);
        int st = (seg == 0) ? 0 : sB[seg];
        int qp1 = g - st + 1;
        float r2 = run[g] - sCz[seg];
        bool seld = (se[g] > r2 / (float)qp1) || (qp1 <= win);
        sFlag[g] = seld ? 1 : 0;
    }
    __syncthreads();

    int CH = (N + 255) >> 8;
    int lo = tid * CH, hi = min(lo + CH, N);
    {
        int s = 0;
        for (int g = lo; g < hi; ++g) s += sFlag[g];
        sSum[tid] = s;
    }
    __syncthreads();
    if (tid == 0) {
        int acc = 0;
        for (int t = 0; t < 256; ++t) { int v = sSum[t]; sSum[t] = acc; acc += v; }
    }
    __syncthreads();

    int* sel = (int*)(g_pool + selOff);
    int* tm  = (int*)(g_pool + tmOff);
    float* eus = g_pool + euSelOff;
    int* bn  = (int*)(g_pool + boundsNextOff);

    int csel0 = sFlag[0];
    {
        int csel = sSum[tid];
        for (int g = lo; g < hi; ++g) {
            csel += sFlag[g];
            tm[g] = csel - csel0;
            if (sFlag[g]) { sel[csel - 1] = g; eus[csel - 1] = se[g]; }
            #pragma unroll
            for (int s = 0; s < NBAT; ++s)
                if (g == sB[s + 1] - 1) sEc[s] = csel;
        }
    }
    __syncthreads();
    if (tid == 0) {
        bn[0] = 0; bn[1] = sEc[0]; bn[2] = sEc[1]; bn[3] = sEc[2]; bn[4] = sEc[3];
    }
}

// ---------------- fused shift-sum(d) + r-softmax + dat ----------------
__global__ __launch_bounds__(256) void k_rdat(
    size_t boundsOff, size_t bufYOff,
    const float* __restrict__ b1, const float* __restrict__ w2, const float* __restrict__ b2,
    size_t selOff, size_t mdevOff,
    size_t srcOff, int srcStr, const float* __restrict__ buf,
    size_t datOff)
{
    int i = blockIdx.x;
    if (i >= *(const int*)(g_pool + mdevOff)) return;
    const float* src = g_pool + srcOff;
    const int* bounds = (const int*)(g_pool + boundsOff);
    const int* sel = (const int*)(g_pool + selOff);
    float* dat = g_pool + datOff;

    __shared__ float gh[HID];
    __shared__ float sv[WSZ];
    __shared__ float r[WSZ];
    __shared__ int sG, sQp;

    int tid = threadIdx.x;
    if (tid == 0) {
        int g = sel[i];
        int b1i = bounds[1], b2i = bounds[2], b3i = bounds[3];
        int s = (g >= b1i) + (g >= b2i) + (g >= b3i);
        int st = (s == 0) ? 0 : ((s == 1) ? b1i : ((s == 2) ? b2i : b3i));
        sG = g; sQp = g - st;
    }
    __syncthreads();
    int g = sG, qp = sQp;

    if (tid < HID) {
        const float* Y = g_pool + oYB;
        const float* bufY = g_pool + bufYOff;
        float acc = b1[tid];
        #pragma unroll
        for (int j = 0; j < WSZ; ++j) {
            int sp = qp - j;
            const float* row = (sp >= 0) ? &Y[(size_t)(g - j) * NY]
                                         : &bufY[(size_t)(15 + sp) * NY];
            acc += row[NY / 2 + j * HID + tid];
        }
        gh[tid] = geluf(acc);
    }
    __syncthreads();
    if (tid < WSZ) {
        float acc = 0.0f;
        for (int k = 0; k < HID; ++k) acc += gh[k] * w2[k * WSZ + tid];
        sv[tid] = acc + b2[tid];
    }
    __syncthreads();
    if (tid == 0) {
        float m = sv[0];
        for (int t = 1; t < WSZ; ++t) m = fmaxf(m, sv[t]);
        float sum = 0.0f;
        for (int t = 0; t < WSZ; ++t) { float e = expf(sv[t] - m); r[t] = e; sum += e; }
        for (int t = 0; t < WSZ; ++t) r[t] = r[t] / sum;
    }
    __syncthreads();
    for (int f = tid; f < F; f += 256) {
        float acc = 0.0f;
        for (int j = 0; j < WSZ; ++j) {
            int sp = qp - j;
            float v = (sp >= 0) ? src[(size_t)(g - j) * srcStr + f]
                                : buf[(size_t)(15 + sp) * F + f];
            acc = fmaf(r[j], v, acc);
        }
        dat[(size_t)i * F + f] = acc;
    }
}

// ---------------- fused attention over 48 gathered kv slots ----------------
__global__ __launch_bounds__(512) void k_attn(
    const float* __restrict__ bk, const float* __restrict__ bv)
{
    int g = blockIdx.x;
    const float* XO   = g_pool + oXO;
    const float* BH0k = g_pool + oBH0K;
    const float* BH0v = g_pool + oBH0V;
    const float* DH1k = g_pool + oDH1K;
    const float* DH1v = g_pool + oDH1V;
    const float* DH2k = g_pool + oDH2K;
    const float* DH2v = g_pool + oDH2V;
    const float* eus0 = g_pool + oEUS0;
    const float* eus1 = g_pool + oEUS1;
    const int* tm0 = (const int*)(g_pool + oTM0);
    const int* tm1 = (const int*)(g_pool + oTM1);
    const int* bounds1 = (const int*)(g_pool + oB1);
    const int* bounds2 = (const int*)(g_pool + oB2);

    __shared__ const float* sK[48];
    __shared__ const float* sV[48];
    __shared__ float sScale[48];
    __shared__ __align__(16) float sQ[E], sBk[E], sBv[E];
    __shared__ float sc[48][8];

    int tid = threadIdx.x;
    sQ[tid]  = XO[(size_t)g * XSTR + 2048 + tid];
    sBk[tid] = bk[tid];
    sBv[tid] = bv[tid];

    if (tid < 48) {
        int s = tid;
        const float *pK = nullptr, *pV = nullptr;
        float scl = 0.0f;
        if (s < 16) {
            int s0 = (g >= 768) + (g >= 1408) + (g >= 2112);
            const int st0[4] = {0, 768, 1408, 2112};
            int sp = (g - st0[s0]) - s;
            if (sp >= 0) { pK = XO + (size_t)(g - s) * XSTR + 1024; pV = XO + (size_t)(g - s) * XSTR + 1536; }
            else         { pK = BH0k + (size_t)(15 + sp) * E; pV = BH0v + (size_t)(15 + sp) * E; }
            scl = 1.0f;
        } else if (s < 32) {
            int j = s - 16;
            int i1 = tm0[g];
            int b1 = bounds1[1], b2 = bounds1[2], b3 = bounds1[3];
            int sg = (i1 >= b1) + (i1 >= b2) + (i1 >= b3);
            int st = (sg == 0) ? 0 : ((sg == 1) ? b1 : ((sg == 2) ? b2 : b3));
            int sp = (i1 - st) - j;
            if (sp >= 0) { pK = DH1k + (size_t)(i1 - j) * E; pV = DH1v + (size_t)(i1 - j) * E; scl = eus0[i1 - j]; }
        } else {
            int j = s - 32;
            int i1 = tm0[g];
            int i2 = tm1[i1];
            int b1 = bounds2[1], b2 = bounds2[2], b3 = bounds2[3];
            int sg = (i2 >= b1) + (i2 >= b2) + (i2 >= b3);
            int st = (sg == 0) ? 0 : ((sg == 1) ? b1 : ((sg == 2) ? b2 : b3));
            int sp = (i2 - st) - j;
            if (sp >= 0) { pK = DH2k + (size_t)(i2 - j) * E; pV = DH2v + (size_t)(i2 - j) * E; scl = eus1[i2 - j]; }
        }
        sK[s] = pK; sV[s] = pV; sScale[s] = scl;
    }
    __syncthreads();

    if (tid < 384) {
        int s = tid >> 3, h = tid & 7;
        const float* bp = sK[s];
        float scl = sScale[s];
        float acc = 0.0f;
        int d0 = h * 64;
        if (s < 16) {
            for (int d = 0; d < 64; d += 4) {
                float4 qv = *(const float4*)&sQ[d0 + d];
                float4 kv4 = *(const float4*)&bp[d0 + d];
                acc += qv.x * kv4.x; acc += qv.y * kv4.y;
                acc += qv.z * kv4.z; acc += qv.w * kv4.w;
            }
        } else if (bp) {
            for (int d = 0; d < 64; d += 4) {
                float4 qv = *(const float4*)&sQ[d0 + d];
                float4 kv4 = *(const float4*)&bp[d0 + d];
                float4 bb = *(const float4*)&sBk[d0 + d];
                acc += qv.x * (bb.x + scl * kv4.x); acc += qv.y * (bb.y + scl * kv4.y);
                acc += qv.z * (bb.z + scl * kv4.z); acc += qv.w * (bb.w + scl * kv4.w);
            }
        } else {
            for (int d = 0; d < 64; d += 4) {
                float4 qv = *(const float4*)&sQ[d0 + d];
                float4 bb = *(const float4*)&sBk[d0 + d];
                acc += qv.x * bb.x; acc += qv.y * bb.y;
                acc += qv.z * bb.z; acc += qv.w * bb.w;
            }
        }
        sc[s][h] = acc * 0.125f;   // / sqrt(64)
    }
    __syncthreads();

    if (tid < 8) {
        int h = tid;
        float m = sc[0][h];
        for (int s = 1; s < 48; ++s) m = fmaxf(m, sc[s][h]);
        float sum = 0.0f;
        for (int s = 0; s < 48; ++s) { float e = expf(sc[s][h] - m); sc[s][h] = e; sum += e; }
        for (int s = 0; s < 48; ++s) sc[s][h] = sc[s][h] / sum;
    }
    __syncthreads();

    {
        int d = tid, h = d >> 6;
        float acc = 0.0f;
        for (int s = 0; s < 48; ++s) {
            const float* bp = sV[s];
            float vv;
            if (s < 16) vv = bp[d];
            else        vv = sBv[d] + (bp ? sScale[s] * bp[d] : 0.0f);
            acc = fmaf(sc[s][h], vv, acc);
        }
        g_pool[oCTX + (size_t)g * E + d] = acc;
    }
}

// ---------------- y2 -> out (B, 768, E) with zero padding ----------------
__global__ __launch_bounds__(256) void k_scatter(float* __restrict__ out) {
    int idx = blockIdx.x * 256 + threadIdx.x;
    if (idx >= NBAT * MAXL * E) return;
    int d = idx & (E - 1);
    int rest = idx >> 9;
    int p = rest % MAXL, bb = rest / MAXL;
    const int st[4] = {0, 768, 1408, 2112};
    const int ln[4] = {768, 640, 704, 600};
    out[idx] = (p < ln[bb]) ? g_pool[oY2 + (size_t)(st[bb] + p) * E + d] : 0.0f;
}

// ================================================================================
extern "C" void kernel_launch(void* const* d_in, const int* in_sizes, int n_in,
                              void* d_out, int out_size, void* d_ws, size_t ws_size,
                              hipStream_t stream)
{
    (void)in_sizes; (void)n_in; (void)d_ws; (void)ws_size; (void)out_size;

    const float* x      = (const float*)d_in[0];
    const float* kv_w   = (const float*)d_in[2];
    const float* kv_b   = (const float*)d_in[3];
    const float* q_w    = (const float*)d_in[4];
    const float* q_b    = (const float*)d_in[5];
    const float* proj_w = (const float*)d_in[6];
    const float* proj_b = (const float*)d_in[7];
    const float* buf0   = (const float*)d_in[8];
    const float* buf1   = (const float*)d_in[9];
    const float* d0_w1  = (const float*)d_in[11];
    const float* d0_b1  = (const float*)d_in[12];
    const float* d0_w2  = (const float*)d_in[13];
    const float* d0_b2  = (const float*)d_in[14];
    const float* u0_w1  = (const float*)d_in[15];
    const float* u0_b1  = (const float*)d_in[16];
    const float* u0_w2  = (const float*)d_in[17];
    const float* u0_b2  = (const float*)d_in[18];
    const float* d1_w1  = (const float*)d_in[19];
    const float* d1_b1  = (const float*)d_in[20];
    const float* d1_w2  = (const float*)d_in[21];
    const float* d1_b2  = (const float*)d_in[22];
    const float* u1_w1  = (const float*)d_in[23];
    const float* u1_b1  = (const float*)d_in[24];
    const float* u1_w2  = (const float*)d_in[25];
    const float* u1_b2  = (const float*)d_in[26];
    const float* wq     = (const float*)d_in[27];
    const float* bq     = (const float*)d_in[28];
    const float* wk     = (const float*)d_in[29];
    const float* bk     = (const float*)d_in[30];
    const float* wv     = (const float*)d_in[31];
    const float* bv     = (const float*)d_in[32];
    const float* out_w  = (const float*)d_in[33];
    const float* out_b  = (const float*)d_in[34];

    auto cdiv = [](int a, int b) { return (a + b - 1) / b; };
    auto GT = [&](int M, int N) { return dim3(cdiv(M, 128), cdiv(N, 128)); };

    k_init<<<1, 64, 0, stream>>>();
    k_xflat<<<cdiv(N0 * E, 256), 256, 0, stream>>>(x);

    // ---- weight prep ----
    k_reshape<<<cdiv(F * NY, 256), 256, 0, stream>>>(u0_w1, d0_w1, oBD0);
    k_reshape<<<cdiv(F * NY, 256), 256, 0, stream>>>(u1_w1, d1_w1, oBD1);
    k_copymat<<<cdiv(E * F, 256), 256, 0, stream>>>(kv_w, oWX, E, F, F, XSTR);
    k_wprep<<<dim3(8, 8, 4), 256, 0, stream>>>(kv_w, q_w, out_w, wk, wv, wq, proj_w);
    k_prepvec<<<cdiv(3072, 256), 256, 0, stream>>>(kv_b, q_b, out_b, wk, bk, wv, bv, wq, bq, proj_w, proj_b);
    k_bufy<<<dim3(1, NY / 64, 2), 256, 0, stream>>>(buf0, buf1);
    k_bh<<<dim3(1, E / 64, 2), 256, 0, stream>>>(buf0, wk, bk, wv, bv);

    // ---- X-GEMM: XO = xf @ WX + XB  -> [kv0 | KH0 | VH0 | qh] ----
    k_tgemm<<<GT(N0, XSTR), 256, 0, stream>>>(oXF, E, oWX, XSTR, oXB, oXO, XSTR, N0, NOFF, E);

    // ---- level 0 ----
    k_tgemm<<<GT(N0, NY), 256, 0, stream>>>(oXO, XSTR, oBD0, NY, NOFF, oYB, NY, N0, NOFF, F);
    k_huev<<<N0, 160, 0, stream>>>(oB0, oBUFY0, u0_b1, u0_w2, u0_b2, oEU0, NOFF, N0);
    k_select<<<1, 256, 0, stream>>>(oEU0, oB0, WSZ, oSEL0, oTM0, oEUS0, oB1);
    k_rdat<<<N0, 256, 0, stream>>>(oB0, oBUFY0, d0_b1, d0_w2, d0_b2, oSEL0, oB1 + 4, oXO, XSTR, buf0, oDAT1);

    // ---- level 1 ----
    k_tgemm<<<GT(N0, NY), 256, 0, stream>>>(oDAT1, F, oBD1, NY, NOFF, oYB, NY, N0, oB1 + 4, F);
    k_huev<<<N0, 160, 0, stream>>>(oB1, oBUFY1, u1_b1, u1_w2, u1_b2, oEU1, oB1 + 4, N0);
    k_select<<<1, 256, 0, stream>>>(oEU1, oB1, WSZ, oSEL1, oTM1, oEUS1, oB2);
    k_rdat<<<N0, 256, 0, stream>>>(oB1, oBUFY1, d1_b1, d1_w2, d1_b2, oSEL1, oB2 + 4, oDAT1, F, buf1, oDAT2);

    // ---- DH projections (z-batched, 64-tile) ----
    k_zgemm<<<dim3(cdiv(N0, 64), E / 64, 4), 256, 0, stream>>>(wk, wv);

    // ---- fused attention + combined output projection + scatter ----
    k_attn<<<N0, 512, 0, stream>>>(bk, bv);
    k_pgemm<<<dim3(cdiv(N0, 64), E / 64), 256, 0, stream>>>(oCTX, E, oWOP, E, oBOP, oY2, E, N0, NOFF, E, E);
    k_scatter<<<cdiv(NBAT * MAXL * E, 256), 256, 0, stream>>>((float*)d_out);
}